// Round 1
// baseline (134617.798 us; speedup 1.0000x reference)
//
#include <hip/hip_runtime.h>
#include <hip/hip_cooperative_groups.h>

namespace cg = cooperative_groups;

// ---- problem constants ----
#define NBATCH 16
#define SMEM   256   // encoder length S
#define TSTEPS 400
#define PRE    256
#define ENCS   512
#define AR     1024
#define ATTD   128
#define NFILT  32
#define KCONV  31

// ---- workspace layout (float offsets) ----
#define WS_XS      0u           // 400*16*256   = 1,638,400
#define WS_PM      1638400u     // 16*256*128   =   524,288
#define WS_PA      2162688u     // 16*256*128   =   524,288
#define WS_STATE   2686976u     //                122,880
#define WS_W1T     2809856u     // 80*256       =    20,480
#define WS_W2T     2830336u     // 256*256      =    65,536
#define WS_WLDT    2895872u     // 32*128       =     4,096
// state sub-offsets (relative to WS_STATE)
#define ST_AH0   0
#define ST_AH1   16384
#define ST_AC    32768
#define ST_DH0   49152
#define ST_DH1   65536
#define ST_DC    81920
#define ST_AW    98304
#define ST_AWC   102400
#define ST_CTX0  106496
#define ST_CTX1  114688
#define ST_TOTAL 122880

struct Ptrs {
  const float *memory, *dec_in, *Wpre1, *Wpre2, *Wih_a, *Whh_a, *bih_a, *bhh_a,
              *Wq, *Wm, *v, *Wc, *Wld, *Wih_d, *Whh_d, *bih_d, *bhh_d,
              *Wproj, *bproj, *Wgate, *bgate;
  const int *mlen;
  float *ws;
  float *out;
};

__device__ __forceinline__ float ftanh(float x) {
  float e = __expf(2.f * x);
  return 1.f - 2.f / (e + 1.f);
}
__device__ __forceinline__ float fsig(float x) { return 1.f / (1.f + __expf(-x)); }

__device__ __forceinline__ void fma4(float4& acc, const float4 w, const float4 x) {
  acc.x = fmaf(w.x, x.x, acc.x);
  acc.y = fmaf(w.y, x.y, acc.y);
  acc.z = fmaf(w.z, x.z, acc.z);
  acc.w = fmaf(w.w, x.w, acc.w);
}
__device__ __forceinline__ float hsum4(const float4 a) { return (a.x + a.y) + (a.z + a.w); }

// ---------------- zero state ----------------
__global__ __launch_bounds__(256) void k_zero(Ptrs p) {
  int i = blockIdx.x * 256 + threadIdx.x;
  if (i < ST_TOTAL) p.ws[WS_STATE + i] = 0.f;
}

// ---------------- weight transposes ----------------
__global__ __launch_bounds__(256) void k_transpose(Ptrs p) {
  int i = blockIdx.x * 256 + threadIdx.x;
  if (i < 20480) {                       // W1T[m][p] = Wpre1[p][m]
    int m = i >> 8, c = i & 255;
    p.ws[WS_W1T + i] = p.Wpre1[c * 80 + m];
  } else if (i < 20480 + 65536) {        // W2T[p][q] = Wpre2[q][p]
    int j = i - 20480;
    int pp = j >> 8, q = j & 255;
    p.ws[WS_W2T + j] = p.Wpre2[q * 256 + pp];
  } else if (i < 20480 + 65536 + 4096) { // WldT[f][a] = Wld[a][f]
    int j = i - 20480 - 65536;
    int f = j >> 7, a = j & 127;
    p.ws[WS_WLDT + j] = p.Wld[a * 32 + f];
  }
}

// ---------------- prenet: xs[t][b][:] = relu(relu(di@W1.T)@W2.T) ----------------
__global__ __launch_bounds__(256) void k_prenet(Ptrs p) {
  __shared__ float dil[NBATCH * 80];
  __shared__ float h1[NBATCH * 256];
  const int t = blockIdx.x, tid = threadIdx.x;
  const float* W1T = p.ws + WS_W1T;
  const float* W2T = p.ws + WS_W2T;

  for (int i = tid; i < NBATCH * 80; i += 256) {
    int b = i / 80, m = i - b * 80;
    dil[i] = (t == 0) ? 0.f : p.dec_in[((size_t)b * 80 + m) * 400 + (t - 1)];
  }
  __syncthreads();

  float acc[NBATCH];
#pragma unroll
  for (int b = 0; b < NBATCH; ++b) acc[b] = 0.f;
  for (int m = 0; m < 80; ++m) {
    float w = W1T[m * 256 + tid];
#pragma unroll
    for (int b = 0; b < NBATCH; ++b) acc[b] = fmaf(dil[b * 80 + m], w, acc[b]);
  }
#pragma unroll
  for (int b = 0; b < NBATCH; ++b) h1[b * 256 + tid] = fmaxf(acc[b], 0.f);
  __syncthreads();

#pragma unroll
  for (int b = 0; b < NBATCH; ++b) acc[b] = 0.f;
  for (int q = 0; q < 256; ++q) {
    float w = W2T[q * 256 + tid];
#pragma unroll
    for (int b = 0; b < NBATCH; ++b) acc[b] = fmaf(h1[b * 256 + q], w, acc[b]);
  }
  float* xs = p.ws + WS_XS;
#pragma unroll
  for (int b = 0; b < NBATCH; ++b)
    xs[((size_t)(t * NBATCH + b)) * 256 + tid] = fmaxf(acc[b], 0.f);
}

// ---------------- proc_mem[b][s][a] = memory[b][s][:] . Wm[a][:] ----------------
__global__ __launch_bounds__(256) void k_procmem(Ptrs p) {
  __shared__ alignas(16) float msl[16 * ENCS]; // 32 KB
  const int b = blockIdx.x >> 4, s0 = (blockIdx.x & 15) << 4;
  const int tid = threadIdx.x;
  const float4* src = (const float4*)(p.memory + ((size_t)(b * SMEM + s0)) * ENCS);
  float4* dst = (float4*)msl;
  for (int i = tid; i < 16 * ENCS / 4; i += 256) dst[i] = src[i];
  __syncthreads();

  const int a = tid & 127, sg = tid >> 7;
  const float4* wm = (const float4*)(p.Wm + (size_t)a * ENCS);
  float* pm = p.ws + WS_PM;
  float4 acc[8];
#pragma unroll
  for (int j = 0; j < 8; ++j) acc[j] = make_float4(0.f, 0.f, 0.f, 0.f);
  for (int k = 0; k < ENCS / 4; ++k) {
    float4 w = wm[k];
#pragma unroll
    for (int j = 0; j < 8; ++j) {
      float4 m = ((const float4*)(msl + (size_t)(sg * 8 + j) * ENCS))[k];
      fma4(acc[j], w, m);
    }
  }
#pragma unroll
  for (int j = 0; j < 8; ++j)
    pm[((size_t)(b * SMEM + s0 + sg * 8 + j)) * ATTD + a] = hsum4(acc[j]);
}

// ---------------- persistent scan kernel ----------------
__global__ __launch_bounds__(512) void k_scan(Ptrs p) {
  cg::grid_group grid = cg::this_grid();
  __shared__ alignas(16) float sm[1600];
  const int bid = blockIdx.x, tid = threadIdx.x;

  float* ws = p.ws;
  float* xs = ws + WS_XS;
  float* pm = ws + WS_PM;
  float* pa = ws + WS_PA;
  float* ST = ws + WS_STATE;
  float* acst = ST + ST_AC;
  float* dcst = ST + ST_DC;
  float* aw  = ST + ST_AW;
  float* awc = ST + ST_AWC;
  const float* WldT = ws + WS_WLDT;
  float* out_mel  = p.out;
  float* out_gate = p.out + 512000;
  float* out_al   = p.out + 518400;

  for (int t = 0; t <= TSTEPS; ++t) {
    const int tb = t & 1;
    float* ah_prev  = ST + (tb ? ST_AH1 : ST_AH0);   // ah(t-1)
    float* ah_cur   = ST + (tb ? ST_AH0 : ST_AH1);   // ah(t)  (written this step)
    float* dh_prev  = ST + (tb ? ST_DH0 : ST_DH1);   // dh(t-2)
    float* dh_cur   = ST + (tb ? ST_DH1 : ST_DH0);   // dh(t-1) (written this step)
    float* ctx_prev = ST + (tb ? ST_CTX0 : ST_CTX1); // ctx(t-1)
    float* ctx_cur  = ST + (tb ? ST_CTX1 : ST_CTX0); // ctx(t)  (written this step)

    // ================= Phase 1 =================
    if (bid < 128) {
      if (t < TSTEPS) {
        // ---- attention LSTM, step t: z = [x|ctx(t-1)]@Wih_a.T + ah(t-1)@Whh_a.T + b
        const int pr = tid >> 2, g = tid & 3;
        const int n = (bid << 3) | (pr >> 4);
        const int b = pr & 15;
        const int row = (g << 10) | n;
        float4 a4 = make_float4(0.f, 0.f, 0.f, 0.f);
        const float4* w1 = (const float4*)(p.Wih_a + (size_t)row * 768);
        const float4* xv = (const float4*)(xs + ((size_t)(t * NBATCH + b)) * 256);
#pragma unroll 4
        for (int k = 0; k < 64; ++k) fma4(a4, w1[k], xv[k]);
        const float4* cxv = (const float4*)(ctx_prev + (b << 9));
#pragma unroll 4
        for (int k = 0; k < 128; ++k) fma4(a4, w1[64 + k], cxv[k]);
        const float4* w2 = (const float4*)(p.Whh_a + ((size_t)row << 10));
        const float4* hv = (const float4*)(ah_prev + (b << 10));
#pragma unroll 4
        for (int k = 0; k < 256; ++k) fma4(a4, w2[k], hv[k]);
        sm[tid] = hsum4(a4) + p.bih_a[row] + p.bhh_a[row];
        __syncthreads();
        if (tid < 128) {
          const int n2 = (bid << 3) | (tid >> 4), b2 = tid & 15;
          const int idx = (b2 << 10) | n2;
          float zi = sm[(tid << 2)], zf = sm[(tid << 2) | 1];
          float zg = sm[(tid << 2) | 2], zo = sm[(tid << 2) | 3];
          float cn = fsig(zf) * acst[idx] + fsig(zi) * ftanh(zg);
          acst[idx] = cn;
          ah_cur[idx] = fsig(zo) * ftanh(cn);
        }
        // ---- location conv (uses aw(t-1), awc(t-1)); 2 (b,s-chunk16) units/block
        {
          const int f = tid >> 4, si = tid & 15;
#pragma unroll
          for (int u = 0; u < 2; ++u) {
            const int unit = (bid << 1) | u;
            const int b3 = unit >> 4;
            const int s = ((unit & 15) << 4) + si;
            float acc2 = 0.f;
            const float* wcf = p.Wc + f * 62;
            for (int k = 0; k < KCONV; ++k) {
              int sp = s - 15 + k;
              if (sp >= 0 && sp < SMEM) {
                acc2 = fmaf(aw[b3 * SMEM + sp], wcf[k], acc2);
                acc2 = fmaf(awc[b3 * SMEM + sp], wcf[31 + k], acc2);
              }
            }
            sm[512 + (u << 9) + (f << 4) + si] = acc2;
          }
        }
        __syncthreads();
        // ---- proc_att[b][s][a] = sum_f loc[f][s] * Wld[a][f]
        {
          const int a2 = tid & 127;
          for (int i = tid; i < 4096; i += 512) {
            const int u = i >> 11, si = (i >> 7) & 15;
            const int unit = (bid << 1) | u;
            const int b3 = unit >> 4;
            const int s = ((unit & 15) << 4) + si;
            float acc3 = 0.f;
            const float* lp = sm + 512 + (u << 9) + si;
#pragma unroll
            for (int f2 = 0; f2 < NFILT; ++f2)
              acc3 = fmaf(lp[f2 << 4], WldT[(f2 << 7) + a2], acc3);
            pa[((size_t)(b3 * SMEM + s)) * ATTD + a2] = acc3;
          }
        }
      }
    } else {
      if (t >= 1) {
        // ---- decoder LSTM, step t-1: z = [ah(t-1)|ctx(t-1)]@Wih_d.T + dh(t-2)@Whh_d.T + b
        const int bb = bid - 128;
        const int pr = tid >> 2, g = tid & 3;
        const int n = (bb << 3) | (pr >> 4);
        const int b = pr & 15;
        const int row = (g << 10) | n;
        float4 a4 = make_float4(0.f, 0.f, 0.f, 0.f);
        const float4* w1 = (const float4*)(p.Wih_d + (size_t)row * 1536);
        const float4* hv = (const float4*)(ah_prev + (b << 10));
#pragma unroll 4
        for (int k = 0; k < 256; ++k) fma4(a4, w1[k], hv[k]);
        const float4* cxv = (const float4*)(ctx_prev + (b << 9));
#pragma unroll 4
        for (int k = 0; k < 128; ++k) fma4(a4, w1[256 + k], cxv[k]);
        const float4* w2 = (const float4*)(p.Whh_d + ((size_t)row << 10));
        const float4* dv = (const float4*)(dh_prev + (b << 10));
#pragma unroll 4
        for (int k = 0; k < 256; ++k) fma4(a4, w2[k], dv[k]);
        sm[tid] = hsum4(a4) + p.bih_d[row] + p.bhh_d[row];
        __syncthreads();
        if (tid < 128) {
          const int n2 = (bb << 3) | (tid >> 4), b2 = tid & 15;
          const int idx = (b2 << 10) | n2;
          float zi = sm[(tid << 2)], zf = sm[(tid << 2) | 1];
          float zg = sm[(tid << 2) | 2], zo = sm[(tid << 2) | 3];
          float cn = fsig(zf) * dcst[idx] + fsig(zi) * ftanh(zg);
          dcst[idx] = cn;
          dh_cur[idx] = fsig(zo) * ftanh(cn);
        }
      }
    }
    grid.sync();

    // ================= Phase 2 =================
    if (bid < 16) {
      if (t < TSTEPS) {
        const int b = bid;
        // ---- q = ah(t) @ Wq.T  (128 dots of 1024)
        if (tid < 128) {
          float4 a4 = make_float4(0.f, 0.f, 0.f, 0.f);
          const float4* wq = (const float4*)(p.Wq + (size_t)tid * AR);
          const float4* hv = (const float4*)(ah_cur + (b << 10));
#pragma unroll 4
          for (int k = 0; k < 256; ++k) fma4(a4, wq[k], hv[k]);
          sm[tid] = hsum4(a4);
        }
        __syncthreads();
        // ---- e[s] = v . tanh(q + pa + pm), masked
        float e = -3.0e38f;
        if (tid < 256) {
          const int s = tid;
          float acc = 0.f;
          const float4* qv = (const float4*)sm;
          const float4* pav = (const float4*)(pa + ((size_t)(b * SMEM + s)) * ATTD);
          const float4* pmv = (const float4*)(pm + ((size_t)(b * SMEM + s)) * ATTD);
          const float4* vv = (const float4*)p.v;
#pragma unroll 4
          for (int k = 0; k < 32; ++k) {
            float4 q4 = qv[k], a4 = pav[k], m4 = pmv[k], v4 = vv[k];
            acc = fmaf(v4.x, ftanh(q4.x + a4.x + m4.x), acc);
            acc = fmaf(v4.y, ftanh(q4.y + a4.y + m4.y), acc);
            acc = fmaf(v4.z, ftanh(q4.z + a4.z + m4.z), acc);
            acc = fmaf(v4.w, ftanh(q4.w + a4.w + m4.w), acc);
          }
          if (s >= p.mlen[b]) acc = -1.0e9f;
          e = acc;
        }
        // ---- softmax (8 waves: shfl reduce + LDS combine)
        float m = e;
        for (int o = 32; o > 0; o >>= 1) m = fmaxf(m, __shfl_xor(m, o));
        if ((tid & 63) == 0) sm[1280 + (tid >> 6)] = m;
        __syncthreads();
        float gmax = sm[1280];
#pragma unroll
        for (int w = 1; w < 8; ++w) gmax = fmaxf(gmax, sm[1280 + w]);
        float pv = (tid < 256) ? __expf(e - gmax) : 0.f;
        float sum = pv;
        for (int o = 32; o > 0; o >>= 1) sum += __shfl_xor(sum, o);
        if ((tid & 63) == 0) sm[1288 + (tid >> 6)] = sum;
        __syncthreads();
        float gsum = 0.f;
#pragma unroll
        for (int w = 0; w < 8; ++w) gsum += sm[1288 + w];
        float awv = pv / gsum;
        if (tid < 256) {
          aw[b * SMEM + tid] = awv;
          awc[b * SMEM + tid] += awv;
          out_al[((size_t)(b * TSTEPS + t)) * SMEM + tid] = awv;
          sm[tid] = awv;
        }
        __syncthreads();
        // ---- ctx(t) = sum_s aw[s] * memory[b][s][:]
        {
          float acc = 0.f;
          const float* mb = p.memory + ((size_t)b * SMEM) * ENCS + tid;
          for (int s = 0; s < SMEM; ++s) acc = fmaf(sm[s], mb[(size_t)s * ENCS], acc);
          ctx_cur[(b << 9) + tid] = acc;
        }
      }
    } else if (bid < 22) {
      if (t >= 1) {
        // ---- projection for step t-1: hac = [dh(t-1)|ctx(t-1)]; 2 threads/dot
        const int idx = ((bid - 16) << 8) | (tid >> 1);
        const int half = tid & 1;
        if (idx < 1296) {
          int mrow = 0, b2;
          const float* wrow;
          float bias;
          if (idx < 1280) {
            mrow = idx >> 4; b2 = idx & 15;
            wrow = p.Wproj + (size_t)mrow * 1536;
            bias = p.bproj[mrow];
          } else {
            b2 = idx - 1280;
            wrow = p.Wgate;
            bias = p.bgate[0];
          }
          const float4* w4 = (const float4*)wrow;
          const float4* h4 = (const float4*)(dh_cur + (b2 << 10));
          const float4* c4 = (const float4*)(ctx_prev + (b2 << 9));
          float4 a4 = make_float4(0.f, 0.f, 0.f, 0.f);
          if (half == 0) {
#pragma unroll 4
            for (int k = 0; k < 192; ++k) fma4(a4, w4[k], h4[k]);
          } else {
#pragma unroll 4
            for (int k = 192; k < 256; ++k) fma4(a4, w4[k], h4[k]);
#pragma unroll 4
            for (int k = 0; k < 128; ++k) fma4(a4, w4[256 + k], c4[k]);
          }
          float acc = hsum4(a4);
          float other = __shfl_xor(acc, 1);
          if (half == 0) {
            float r = acc + other + bias;
            if (idx < 1280)
              out_mel[((size_t)b2 * 80 + mrow) * TSTEPS + (t - 1)] = r;
            else
              out_gate[(size_t)b2 * TSTEPS + (t - 1)] = r;
          }
        }
      }
    }
    if (t < TSTEPS) grid.sync();
  }
}

extern "C" void kernel_launch(void* const* d_in, const int* in_sizes, int n_in,
                              void* d_out, int out_size, void* d_ws, size_t ws_size,
                              hipStream_t stream) {
  (void)in_sizes; (void)n_in; (void)out_size; (void)ws_size;
  Ptrs p;
  p.memory = (const float*)d_in[0];
  p.dec_in = (const float*)d_in[1];
  p.Wpre1  = (const float*)d_in[2];
  p.Wpre2  = (const float*)d_in[3];
  p.Wih_a  = (const float*)d_in[4];
  p.Whh_a  = (const float*)d_in[5];
  p.bih_a  = (const float*)d_in[6];
  p.bhh_a  = (const float*)d_in[7];
  p.Wq     = (const float*)d_in[8];
  p.Wm     = (const float*)d_in[9];
  p.v      = (const float*)d_in[10];
  p.Wc     = (const float*)d_in[11];
  p.Wld    = (const float*)d_in[12];
  p.Wih_d  = (const float*)d_in[13];
  p.Whh_d  = (const float*)d_in[14];
  p.bih_d  = (const float*)d_in[15];
  p.bhh_d  = (const float*)d_in[16];
  p.Wproj  = (const float*)d_in[17];
  p.bproj  = (const float*)d_in[18];
  p.Wgate  = (const float*)d_in[19];
  p.bgate  = (const float*)d_in[20];
  p.mlen   = (const int*)d_in[21];
  p.ws  = (float*)d_ws;
  p.out = (float*)d_out;

  hipLaunchKernelGGL(k_zero,      dim3(480), dim3(256), 0, stream, p);
  hipLaunchKernelGGL(k_transpose, dim3(352), dim3(256), 0, stream, p);
  hipLaunchKernelGGL(k_prenet,    dim3(400), dim3(256), 0, stream, p);
  hipLaunchKernelGGL(k_procmem,   dim3(256), dim3(256), 0, stream, p);

  void* kargs[] = { (void*)&p };
  hipLaunchCooperativeKernel(reinterpret_cast<const void*>(&k_scan),
                             dim3(256), dim3(512), kargs, 0, stream);
}

// Round 3
// 67710.278 us; speedup vs baseline: 1.9881x; 1.9881x over previous
//
#include <hip/hip_runtime.h>

typedef unsigned short ushort_t;
typedef float f32x4_t __attribute__((ext_vector_type(4)));
typedef short bf16x8_t __attribute__((ext_vector_type(8)));

// ---- problem constants ----
#define NBATCH 16
#define SMEM   256
#define TSTEPS 400

// ---- workspace layout (float offsets) ----
#define F_XSB   0u         // 400*16*256 bf16 = 819200 floats
#define F_PM    819200u    // 16*256*128 f32
#define F_PAPM  1343488u   // 16*256*128 f32
#define F_W1T   1867776u   // 80*256
#define F_W2T   1888256u   // 256*256
// ---- zeroed region start ----
#define F_LOC   1953792u   // 16*256*32 bf16 = 65536 floats
#define F_AW    2019328u   // 4096 (reserved/unused)
#define F_AWC   2023424u   // 4096 (reserved/unused)
#define F_AHB   2027520u   // 2 bufs * 16*1024 bf16 = 16384 floats
#define F_DHB   2043904u   // 2 bufs * 16*1024 bf16 = 16384 floats
#define F_CTXB  2060288u   // 2 bufs * 16*512 bf16 = 8192 floats
#define F_CTXF  2068480u   // 2 bufs * 16*512 f32 = 16384 floats
#define F_BAR   2084864u   // 16 (barrier state, ints)
// ---- zeroed region end (131088 floats) ----
#define F_DHF   2084880u   // 2 bufs * 16*1024 f32 = 32768
// total 2117648 floats ~= 8.47 MB
#define ZERO_BASE  F_LOC
#define ZERO_COUNT 131088u

struct Ptrs {
  const float *memory, *dec_in, *Wpre1, *Wpre2, *Wih_a, *Whh_a, *bih_a, *bhh_a,
              *Wq, *Wm, *v, *Wc, *Wld, *Wih_d, *Whh_d, *bih_d, *bhh_d,
              *Wproj, *bproj, *Wgate, *bgate;
  const int *mlen;
  float *ws;
  float *out;
};

__device__ __forceinline__ float ftanh(float x) {
  float e = __expf(2.f * x);
  return 1.f - 2.f / (e + 1.f);
}
__device__ __forceinline__ float fsig(float x) { return 1.f / (1.f + __expf(-x)); }

__device__ __forceinline__ unsigned f2bfbits(float x) {
  unsigned u = __builtin_bit_cast(unsigned, x);
  return (u + 0x7FFFu + ((u >> 16) & 1u)) >> 16;
}
__device__ __forceinline__ bf16x8_t packbf8(const float* f) {
  bf16x8_t r;
#pragma unroll
  for (int j = 0; j < 8; ++j) r[j] = (short)f2bfbits(f[j]);
  return r;
}
__device__ __forceinline__ bf16x8_t pack_from_f4(const float* src) {
  const float4* s4 = (const float4*)src;
  float4 lo = s4[0], hi = s4[1];
  float tmp[8] = {lo.x, lo.y, lo.z, lo.w, hi.x, hi.y, hi.z, hi.w};
  return packbf8(tmp);
}
__device__ __forceinline__ bf16x8_t ldbf8(const ushort_t* p) {
  return *(const bf16x8_t*)p;
}
#define MFMA16(a,b,c) __builtin_amdgcn_mfma_f32_16x16x32_bf16((a),(b),(c),0,0,0)

// ---- grid barrier (sense-reversing, device scope) ----
__device__ __forceinline__ void gbar(int* bar) {
  __syncthreads();
  if (threadIdx.x == 0) {
    __threadfence();
    int g = __hip_atomic_load(bar + 1, __ATOMIC_RELAXED, __HIP_MEMORY_SCOPE_AGENT);
    int a = __hip_atomic_fetch_add(bar, 1, __ATOMIC_ACQ_REL, __HIP_MEMORY_SCOPE_AGENT);
    if (a == 255) {
      __hip_atomic_store(bar, 0, __ATOMIC_RELAXED, __HIP_MEMORY_SCOPE_AGENT);
      __hip_atomic_store(bar + 1, g + 1, __ATOMIC_RELEASE, __HIP_MEMORY_SCOPE_AGENT);
    } else {
      while (__hip_atomic_load(bar + 1, __ATOMIC_ACQUIRE, __HIP_MEMORY_SCOPE_AGENT) == g)
        __builtin_amdgcn_s_sleep(1);
    }
    __threadfence();
  }
  __syncthreads();
}

// ---------------- zero state ----------------
__global__ __launch_bounds__(256) void k_zero(Ptrs p) {
  unsigned i = blockIdx.x * 256 + threadIdx.x;
  if (i < ZERO_COUNT) p.ws[ZERO_BASE + i] = 0.f;
}

// ---------------- weight transposes for prenet ----------------
__global__ __launch_bounds__(256) void k_transpose(Ptrs p) {
  int i = blockIdx.x * 256 + threadIdx.x;
  if (i < 20480) {
    int m = i >> 8, c = i & 255;
    p.ws[F_W1T + i] = p.Wpre1[c * 80 + m];
  } else if (i < 20480 + 65536) {
    int j = i - 20480;
    int pp = j >> 8, q = j & 255;
    p.ws[F_W2T + j] = p.Wpre2[q * 256 + pp];
  }
}

// ---------------- prenet -> xsb (bf16) ----------------
__global__ __launch_bounds__(256) void k_prenet(Ptrs p) {
  __shared__ float dil[NBATCH * 80];
  __shared__ float h1[NBATCH * 256];
  const int t = blockIdx.x, tid = threadIdx.x;
  const float* W1T = p.ws + F_W1T;
  const float* W2T = p.ws + F_W2T;

  for (int i = tid; i < NBATCH * 80; i += 256) {
    int b = i / 80, m = i - b * 80;
    dil[i] = (t == 0) ? 0.f : p.dec_in[((size_t)b * 80 + m) * 400 + (t - 1)];
  }
  __syncthreads();

  float acc[NBATCH];
#pragma unroll
  for (int b = 0; b < NBATCH; ++b) acc[b] = 0.f;
  for (int m = 0; m < 80; ++m) {
    float w = W1T[m * 256 + tid];
#pragma unroll
    for (int b = 0; b < NBATCH; ++b) acc[b] = fmaf(dil[b * 80 + m], w, acc[b]);
  }
#pragma unroll
  for (int b = 0; b < NBATCH; ++b) h1[b * 256 + tid] = fmaxf(acc[b], 0.f);
  __syncthreads();

#pragma unroll
  for (int b = 0; b < NBATCH; ++b) acc[b] = 0.f;
  for (int q = 0; q < 256; ++q) {
    float w = W2T[q * 256 + tid];
#pragma unroll
    for (int b = 0; b < NBATCH; ++b) acc[b] = fmaf(h1[b * 256 + q], w, acc[b]);
  }
  ushort_t* xsbU = (ushort_t*)(p.ws + F_XSB);
#pragma unroll
  for (int b = 0; b < NBATCH; ++b)
    xsbU[((size_t)(t * NBATCH + b)) * 256 + tid] = (ushort_t)f2bfbits(fmaxf(acc[b], 0.f));
}

// ---------------- proc_mem fp32 ----------------
__global__ __launch_bounds__(256) void k_procmem(Ptrs p) {
  __shared__ alignas(16) float msl[16 * 512];
  const int b = blockIdx.x >> 4, s0 = (blockIdx.x & 15) << 4;
  const int tid = threadIdx.x;
  const float4* src = (const float4*)(p.memory + ((size_t)(b * SMEM + s0)) * 512);
  float4* dst = (float4*)msl;
  for (int i = tid; i < 16 * 512 / 4; i += 256) dst[i] = src[i];
  __syncthreads();

  const int a = tid & 127, sg = tid >> 7;
  const float4* wm = (const float4*)(p.Wm + (size_t)a * 512);
  float* pm = p.ws + F_PM;
  float acc[8];
#pragma unroll
  for (int j = 0; j < 8; ++j) acc[j] = 0.f;
  for (int k = 0; k < 128; ++k) {
    float4 w = wm[k];
#pragma unroll
    for (int j = 0; j < 8; ++j) {
      float4 m = ((const float4*)(msl + (size_t)(sg * 8 + j) * 512))[k];
      acc[j] += w.x * m.x + w.y * m.y + w.z * m.z + w.w * m.w;
    }
  }
#pragma unroll
  for (int j = 0; j < 8; ++j)
    pm[((size_t)(b * SMEM + s0 + sg * 8 + j)) * 128 + a] = acc[j];
}

// ---- pa (proc_att) MFMA task ----
__device__ __forceinline__ void wld_init(int pabase, const float* Wld, int m16, int kq, bf16x8_t* o) {
#pragma unroll
  for (int i = 0; i < 4; ++i) {
    int atile = (pabase + i) & 7;
    o[i] = pack_from_f4(Wld + ((size_t)(atile * 16 + m16)) * 32 + kq * 8);
  }
}
__device__ __forceinline__ void pa_do(int pabase, const bf16x8_t* wLd, int m16, int kq,
                                      const float* pmF, float* papmF, const ushort_t* locU) {
#pragma unroll
  for (int i = 0; i < 4; ++i) {
    int tau = pabase + i;
    int cb = tau >> 7, stile = (tau >> 3) & 15, atile = tau & 7;
    int scol = stile * 16 + m16;
    size_t rowo = ((size_t)cb * 256 + scol) * 128 + atile * 16 + kq * 4;
    f32x4_t acc = *(const f32x4_t*)(pmF + rowo);
    bf16x8_t bf = ldbf8(locU + ((size_t)cb * 256 + scol) * 32 + kq * 8);
    acc = MFMA16(wLd[i], bf, acc);
    *(f32x4_t*)(papmF + rowo) = acc;
  }
}

// ---------------- persistent scan: 256 blocks x 512 threads ----------------
__global__ __launch_bounds__(512, 2) void k_scan(Ptrs p) {
  __shared__ alignas(16) float sm[1536];
  const int bid = blockIdx.x, tid = threadIdx.x;
  const int wid = tid >> 6, lane = tid & 63;
  const int m16 = lane & 15, kq = lane >> 4;

  float* ws = p.ws;
  ushort_t* xsbU  = (ushort_t*)(ws + F_XSB);
  float*    pmF   = ws + F_PM;
  float*    papmF = ws + F_PAPM;
  ushort_t* locU  = (ushort_t*)(ws + F_LOC);
  ushort_t* ahbU  = (ushort_t*)(ws + F_AHB);
  ushort_t* dhbU  = (ushort_t*)(ws + F_DHB);
  ushort_t* ctxbU = (ushort_t*)(ws + F_CTXB);
  float*    ctxfF = ws + F_CTXF;
  float*    dhfF  = ws + F_DHF;
  int*      bar   = (int*)(ws + F_BAR);
  float* out_mel  = p.out;
  float* out_gate = p.out + 512000;
  float* out_al   = p.out + 518400;

  if (bid < 64) {
    // ======== A-path: 8 waves = 4 strips x 2 K-halves ========
    const int ls = wid >> 1, half = wid & 1;
    const int strip = (bid << 2) | ls;                 // 0..255
    const int gA = m16 & 3, jA = m16 >> 2;
    const int wrowA = gA * 1024 + strip * 4 + jA;
    bf16x8_t wA[28];
#pragma unroll
    for (int c = 0; c < 28; ++c) {
      int k0 = (half * 28 + c) * 32 + kq * 8;
      const float* src = (k0 < 768) ? p.Wih_a + (size_t)wrowA * 768 + k0
                                    : p.Whh_a + (size_t)wrowA * 1024 + (k0 - 768);
      wA[c] = pack_from_f4(src);
    }
    const int nnA = strip * 4 + kq;
    float biasA[4];
#pragma unroll
    for (int r = 0; r < 4; ++r) biasA[r] = p.bih_a[r * 1024 + nnA] + p.bhh_a[r * 1024 + nnA];
    float acState = 0.f;
    __syncthreads();

    for (int t = 0; t <= TSTEPS; ++t) {
      // ---- PhX: A-LSTM step t ----
      const bool act = (t < TSTEPS);
      f32x4_t a0 = {0,0,0,0}, a1 = {0,0,0,0};
      if (act) {
        const ushort_t* xsrc = xsbU + ((size_t)t * 16 + m16) * 256;
        const ushort_t* csrc = ctxbU + (size_t)((t - 1) & 1) * 8192 + m16 * 512;
        const ushort_t* hsrc = ahbU + (size_t)((t - 1) & 1) * 16384 + m16 * 1024;
        if (half == 0) {
#pragma unroll
          for (int c = 0; c < 28; ++c) {
            const ushort_t* sp = (c < 8)  ? xsrc + c * 32 + kq * 8
                               : (c < 24) ? csrc + (c - 8) * 32 + kq * 8
                                          : hsrc + (c - 24) * 32 + kq * 8;
            bf16x8_t bf = ldbf8(sp);
            if (c & 1) a1 = MFMA16(wA[c], bf, a1); else a0 = MFMA16(wA[c], bf, a0);
          }
        } else {
#pragma unroll
          for (int c = 0; c < 28; ++c) {
            bf16x8_t bf = ldbf8(hsrc + (4 + c) * 32 + kq * 8);
            if (c & 1) a1 = MFMA16(wA[c], bf, a1); else a0 = MFMA16(wA[c], bf, a0);
          }
#pragma unroll
          for (int r = 0; r < 4; ++r) sm[((ls * 64 + lane) << 2) + r] = a0[r] + a1[r];
        }
      }
      __syncthreads();
      if (act && half == 0) {
        float z[4];
#pragma unroll
        for (int r = 0; r < 4; ++r)
          z[r] = a0[r] + a1[r] + sm[((ls * 64 + lane) << 2) + r] + biasA[r];
        float cn = fsig(z[1]) * acState + fsig(z[0]) * ftanh(z[2]);
        acState = cn;
        float h = fsig(z[3]) * ftanh(cn);
        ahbU[(size_t)(t & 1) * 16384 + m16 * 1024 + nnA] = (ushort_t)f2bfbits(h);
      }
      gbar(bar);
      // ---- PhY: idle ----
      gbar(bar);
    }
  } else if (bid < 192) {
    // ======== D-path: 8 waves = 2 strips x 4 K-quarters ========
    const int ls = wid >> 2, qt = wid & 3;
    const int strip = ((bid - 64) << 1) | ls;          // 0..255
    const int gD = m16 & 3, jD = m16 >> 2;
    const int wrowD = gD * 1024 + strip * 4 + jD;
    bf16x8_t wD[20];
#pragma unroll
    for (int c = 0; c < 20; ++c) {
      int k0 = (qt * 20 + c) * 32 + kq * 8;
      const float* src = (k0 < 1536) ? p.Wih_d + (size_t)wrowD * 1536 + k0
                                     : p.Whh_d + (size_t)wrowD * 1024 + (k0 - 1536);
      wD[c] = pack_from_f4(src);
    }
    const int nnD = strip * 4 + kq;
    float biasD[4];
#pragma unroll
    for (int r = 0; r < 4; ++r) biasD[r] = p.bih_d[r * 1024 + nnD] + p.bhh_d[r * 1024 + nnD];
    float dcState = 0.f;
    __syncthreads();

    for (int t = 0; t <= TSTEPS; ++t) {
      // ---- PhX: D-LSTM step t-1 ----
      const bool act = (t >= 1);
      f32x4_t a0 = {0,0,0,0}, a1 = {0,0,0,0};
      if (act) {
        const ushort_t* hsrc = ahbU + (size_t)((t - 1) & 1) * 16384 + m16 * 1024;
        const ushort_t* csrc = ctxbU + (size_t)((t - 1) & 1) * 8192 + m16 * 512;
        const ushort_t* dsrc = dhbU + (size_t)(t & 1) * 16384 + m16 * 1024;
#define DMFMA(SRC, OFF) { bf16x8_t bf = ldbf8((SRC) + (OFF) * 32 + kq * 8); \
          if (c & 1) a1 = MFMA16(wD[c], bf, a1); else a0 = MFMA16(wD[c], bf, a0); }
        if (qt == 0) {
#pragma unroll
          for (int c = 0; c < 20; ++c) DMFMA(hsrc, c)
        } else if (qt == 1) {
#pragma unroll
          for (int c = 0; c < 20; ++c) { if (c < 12) DMFMA(hsrc, 20 + c) else DMFMA(csrc, c - 12) }
        } else if (qt == 2) {
#pragma unroll
          for (int c = 0; c < 20; ++c) { if (c < 8) DMFMA(csrc, 8 + c) else DMFMA(dsrc, c - 8) }
        } else {
#pragma unroll
          for (int c = 0; c < 20; ++c) DMFMA(dsrc, 12 + c)
        }
#undef DMFMA
        if (qt != 0) {
#pragma unroll
          for (int r = 0; r < 4; ++r)
            sm[(((ls * 3 + qt - 1) * 64 + lane) << 2) + r] = a0[r] + a1[r];
        }
      }
      __syncthreads();
      if (act && qt == 0) {
        float z[4];
#pragma unroll
        for (int r = 0; r < 4; ++r) {
          z[r] = a0[r] + a1[r] + biasD[r];
#pragma unroll
          for (int j = 0; j < 3; ++j) z[r] += sm[(((ls * 3 + j) * 64 + lane) << 2) + r];
        }
        float cn = fsig(z[1]) * dcState + fsig(z[0]) * ftanh(z[2]);
        dcState = cn;
        float h = fsig(z[3]) * ftanh(cn);
        size_t po = (size_t)((t - 1) & 1) * 16384 + m16 * 1024 + nnD;
        dhbU[po] = (ushort_t)f2bfbits(h);
        dhfF[po] = h;
      }
      gbar(bar);
      // ---- PhY: idle ----
      gbar(bar);
    }
  } else if (bid < 208) {
    // ======== ATT path: block per batch; pa in PhX; att+ctx+conv in PhY ========
    const int b = bid - 192;
    const int pabase = ((bid - 192) * 8 + wid) * 4;
    bf16x8_t wLd[4];
    wld_init(pabase, p.Wld, m16, kq, wLd);
    // Wq frags: wave wid covers a-rows [wid*16, wid*16+16)
    bf16x8_t wq[32];
#pragma unroll
    for (int c = 0; c < 32; ++c)
      wq[c] = pack_from_f4(p.Wq + (size_t)(wid * 16 + m16) * 1024 + c * 32 + kq * 8);
    // conv weight frags (both filter halves; k2 = ch*31+k padded to 64)
    bf16x8_t wC[2][2];
#pragma unroll
    for (int ft = 0; ft < 2; ++ft)
#pragma unroll
      for (int ck = 0; ck < 2; ++ck) {
        float tmp[8];
#pragma unroll
        for (int jj = 0; jj < 8; ++jj) {
          int k2 = ck * 32 + kq * 8 + jj;
          float vv = 0.f;
          if (k2 < 62) { int ch = (k2 < 31) ? 0 : 1; int k = k2 - 31 * ch;
            vv = p.Wc[((size_t)(ft * 16 + m16) * 2 + ch) * 31 + k]; }
          tmp[jj] = vv;
        }
        wC[ft][ck] = packbf8(tmp);
      }
    float* qsm  = sm;          // 128
    float* red  = sm + 128;    // 16
    float* vsm  = sm + 144;    // 128
    float* smaw = sm + 272;    // 256
    float* smawc= sm + 528;    // 256
    if (tid < 128) vsm[tid] = p.v[tid];
    if (tid < 256) smawc[tid] = 0.f;
    const int mlenb = p.mlen[b];
    const int s = tid >> 1, ha = tid & 1;
    __syncthreads();

    for (int t = 0; t <= TSTEPS; ++t) {
      // ---- PhX: pa duty ----
      if (t < TSTEPS) pa_do(pabase, wLd, m16, kq, pmF, papmF, locU);
      gbar(bar);
      // ---- PhY: attention ----
      if (t < TSTEPS) {
        // q = Wq @ ah(t)
        {
          f32x4_t acc = {0,0,0,0};
#pragma unroll
          for (int c = 0; c < 32; ++c) {
            bf16x8_t bf = ldbf8(ahbU + (size_t)(t & 1) * 16384 + m16 * 1024 + c * 32 + kq * 8);
            acc = MFMA16(wq[c], bf, acc);
          }
          if (m16 == b) {
#pragma unroll
            for (int r = 0; r < 4; ++r) qsm[wid * 16 + kq * 4 + r] = acc[r];
          }
        }
        __syncthreads();
        // e[s] = v . tanh(q + papm), 2 threads per s
        float e;
        {
          const float* pr = papmF + ((size_t)b * 256 + s) * 128 + ha * 64;
          const float* qq = qsm + ha * 64;
          const float* vv = vsm + ha * 64;
          float acc = 0.f;
#pragma unroll
          for (int kk = 0; kk < 16; ++kk) {
            f32x4_t pz = *(const f32x4_t*)(pr + kk * 4);
            f32x4_t q4 = *(const f32x4_t*)(qq + kk * 4);
            f32x4_t v4 = *(const f32x4_t*)(vv + kk * 4);
            acc = fmaf(v4[0], ftanh(q4[0] + pz[0]), acc);
            acc = fmaf(v4[1], ftanh(q4[1] + pz[1]), acc);
            acc = fmaf(v4[2], ftanh(q4[2] + pz[2]), acc);
            acc = fmaf(v4[3], ftanh(q4[3] + pz[3]), acc);
          }
          acc += __shfl_xor(acc, 1);
          e = (s >= mlenb) ? -1.0e9f : acc;
        }
        // softmax over 256 s (each duplicated x2; odd threads contribute 0 to sum)
        float mv = e;
        for (int o = 32; o; o >>= 1) mv = fmaxf(mv, __shfl_xor(mv, o));
        if (lane == 0) red[wid] = mv;
        __syncthreads();
        float gmax = red[0];
#pragma unroll
        for (int w = 1; w < 8; ++w) gmax = fmaxf(gmax, red[w]);
        float pv = (ha == 0) ? __expf(e - gmax) : 0.f;
        float sv = pv;
        for (int o = 32; o; o >>= 1) sv += __shfl_xor(sv, o);
        if (lane == 0) red[8 + wid] = sv;
        __syncthreads();
        float gsum = 0.f;
#pragma unroll
        for (int w = 0; w < 8; ++w) gsum += red[8 + w];
        if (ha == 0) {
          float awv = pv / gsum;
          smaw[s] = awv;
          smawc[s] += awv;
          out_al[((size_t)b * 400 + t) * 256 + s] = awv;
        }
        __syncthreads();
        // ctx(t) = sum_s aw[s] * memory[b][s][:]
        {
          float acc = 0.f;
          const float* mb = p.memory + (size_t)b * 256 * 512 + tid;
          for (int ss = 0; ss < 256; ++ss) acc = fmaf(smaw[ss], mb[(size_t)ss * 512], acc);
          ctxfF[(size_t)(t & 1) * 8192 + b * 512 + tid] = acc;
          ctxbU[(size_t)(t & 1) * 8192 + b * 512 + tid] = (ushort_t)f2bfbits(acc);
        }
        // conv(t+1) from LDS aw/awc: 4 (stile,ft) tasks per wave
#pragma unroll
        for (int u = 0; u < 4; ++u) {
          int task = wid * 4 + u;            // 0..31
          int stile = task >> 1, ft = task & 1;
          int scol = stile * 16 + m16;
          f32x4_t acc = {0,0,0,0};
#pragma unroll
          for (int ck = 0; ck < 2; ++ck) {
            float tmp[8];
#pragma unroll
            for (int jj = 0; jj < 8; ++jj) {
              int k2 = ck * 32 + kq * 8 + jj;
              float vv = 0.f;
              if (k2 < 62) {
                int ch = (k2 < 31) ? 0 : 1; int k = k2 - 31 * ch;
                int sp = scol + k - 15;
                if (sp >= 0 && sp < 256) vv = (ch ? smawc : smaw)[sp];
              }
              tmp[jj] = vv;
            }
            acc = MFMA16(wC[ft][ck], packbf8(tmp), acc);
          }
#pragma unroll
          for (int r = 0; r < 4; ++r)
            locU[((size_t)b * 256 + scol) * 32 + ft * 16 + kq * 4 + r] = (ushort_t)f2bfbits(acc[r]);
        }
      }
      gbar(bar);
    }
  } else if (bid < 216) {
    // ======== PROJ path: 8 blocks; pa in PhX; projection in PhY ========
    const int pabase = ((bid - 192) * 8 + wid) * 4;
    bf16x8_t wLd[4];
    wld_init(pabase, p.Wld, m16, kq, wLd);
    const int wv = (bid - 208) * 8 + wid;   // 0..63
    int rows[2] = {wv * 2, wv * 2 + 1};
    float wreg[2][24], biasr[2];
#pragma unroll
    for (int rr = 0; rr < 2; ++rr) {
      int row = rows[rr];
      biasr[rr] = 0.f;
#pragma unroll
      for (int j = 0; j < 24; ++j) wreg[rr][j] = 0.f;
      if (row < 80) {
#pragma unroll
        for (int j = 0; j < 24; ++j) wreg[rr][j] = p.Wproj[(size_t)row * 1536 + lane + 64 * j];
        biasr[rr] = p.bproj[row];
      } else if (row == 80) {
#pragma unroll
        for (int j = 0; j < 24; ++j) wreg[rr][j] = p.Wgate[lane + 64 * j];
        biasr[rr] = p.bgate[0];
      }
    }
    __syncthreads();
    for (int t = 0; t <= TSTEPS; ++t) {
      if (t < TSTEPS) pa_do(pabase, wLd, m16, kq, pmF, papmF, locU);
      gbar(bar);
      // ---- PhY: projection for step t-1 ----
      if (t >= 1 && wv <= 40) {
        const size_t pp = (size_t)((t - 1) & 1) * 16384;
        const size_t pc = (size_t)((t - 1) & 1) * 8192;
        for (int b2 = 0; b2 < 16; ++b2) {
          float h[24];
#pragma unroll
          for (int j = 0; j < 24; ++j)
            h[j] = (j < 16) ? dhfF[pp + b2 * 1024 + lane + 64 * j]
                            : ctxfF[pc + b2 * 512 + lane + 64 * (j - 16)];
#pragma unroll
          for (int rr = 0; rr < 2; ++rr) {
            if (rows[rr] > 80) continue;
            float d = 0.f;
#pragma unroll
            for (int j = 0; j < 24; ++j) d = fmaf(wreg[rr][j], h[j], d);
            for (int o = 32; o; o >>= 1) d += __shfl_xor(d, o);
            if (lane == 0) {
              d += biasr[rr];
              if (rows[rr] < 80) out_mel[((size_t)b2 * 80 + rows[rr]) * 400 + (t - 1)] = d;
              else out_gate[(size_t)b2 * 400 + (t - 1)] = d;
            }
          }
        }
      }
      gbar(bar);
    }
  } else {
    // ======== PA-only path ========
    const int pabase = ((bid - 192) * 8 + wid) * 4;
    bf16x8_t wLd[4];
    wld_init(pabase, p.Wld, m16, kq, wLd);
    __syncthreads();
    for (int t = 0; t <= TSTEPS; ++t) {
      if (t < TSTEPS) pa_do(pabase, wLd, m16, kq, pmF, papmF, locU);
      gbar(bar);
      gbar(bar);
    }
  }
}

extern "C" void kernel_launch(void* const* d_in, const int* in_sizes, int n_in,
                              void* d_out, int out_size, void* d_ws, size_t ws_size,
                              hipStream_t stream) {
  (void)in_sizes; (void)n_in; (void)out_size; (void)ws_size;
  Ptrs p;
  p.memory = (const float*)d_in[0];
  p.dec_in = (const float*)d_in[1];
  p.Wpre1  = (const float*)d_in[2];
  p.Wpre2  = (const float*)d_in[3];
  p.Wih_a  = (const float*)d_in[4];
  p.Whh_a  = (const float*)d_in[5];
  p.bih_a  = (const float*)d_in[6];
  p.bhh_a  = (const float*)d_in[7];
  p.Wq     = (const float*)d_in[8];
  p.Wm     = (const float*)d_in[9];
  p.v      = (const float*)d_in[10];
  p.Wc     = (const float*)d_in[11];
  p.Wld    = (const float*)d_in[12];
  p.Wih_d  = (const float*)d_in[13];
  p.Whh_d  = (const float*)d_in[14];
  p.bih_d  = (const float*)d_in[15];
  p.bih_d  = (const float*)d_in[15];
  p.bhh_d  = (const float*)d_in[16];
  p.Wproj  = (const float*)d_in[17];
  p.bproj  = (const float*)d_in[18];
  p.Wgate  = (const float*)d_in[19];
  p.bgate  = (const float*)d_in[20];
  p.mlen   = (const int*)d_in[21];
  p.ws  = (float*)d_ws;
  p.out = (float*)d_out;

  hipLaunchKernelGGL(k_zero,      dim3((ZERO_COUNT + 255) / 256), dim3(256), 0, stream, p);
  hipLaunchKernelGGL(k_transpose, dim3(336), dim3(256), 0, stream, p);
  hipLaunchKernelGGL(k_prenet,    dim3(400), dim3(256), 0, stream, p);
  hipLaunchKernelGGL(k_procmem,   dim3(256), dim3(256), 0, stream, p);

  void* kargs[] = { (void*)&p };
  hipError_t err = hipLaunchCooperativeKernel(reinterpret_cast<const void*>(&k_scan),
                                              dim3(256), dim3(512), kargs, 0, stream);
  if (err != hipSuccess) {
    (void)hipGetLastError();
    hipLaunchKernelGGL(k_scan, dim3(256), dim3(512), 0, stream, p);
  }
}

// Round 4
// 17965.363 us; speedup vs baseline: 7.4932x; 3.7689x over previous
//
#include <hip/hip_runtime.h>

typedef unsigned short ushort_t;
typedef float f32x4_t __attribute__((ext_vector_type(4)));
typedef short bf16x8_t __attribute__((ext_vector_type(8)));

// ---- problem constants ----
#define NBATCH 16
#define SMEM   256
#define TSTEPS 400

// ---- workspace layout (float offsets) ----
#define F_XSB   0u         // 400*16*256 bf16 = 819200 floats
#define F_PM    819200u    // 16*256*128 f32
#define F_PAPM  1343488u   // 16*256*128 f32
#define F_W1T   1867776u   // 80*256
#define F_W2T   1888256u   // 256*256
// ---- zeroed region start ----
#define F_LOC   1953792u   // 16*256*32 bf16 = 65536 floats
#define F_AW    2019328u   // 4096 (reserved/unused)
#define F_AWC   2023424u   // 4096 (reserved/unused)
#define F_AHB   2027520u   // 2 bufs * 16*1024 bf16 = 16384 floats
#define F_DHB   2043904u   // 2 bufs * 16*1024 bf16 = 16384 floats
#define F_CTXB  2060288u   // 2 bufs * 16*512 bf16 = 8192 floats
#define F_CTXF  2068480u   // 2 bufs * 16*512 f32 = 16384 floats
#define F_BAR   2084864u   // 8192 floats: arrive[256*16] ints + release int
// ---- zeroed region end ----
#define F_DHF   2093056u   // 2 bufs * 16*1024 f32 = 32768
// total 2125824 floats ~= 8.5 MB
#define ZERO_BASE  F_LOC
#define ZERO_COUNT 139264u

struct Ptrs {
  const float *memory, *dec_in, *Wpre1, *Wpre2, *Wih_a, *Whh_a, *bih_a, *bhh_a,
              *Wq, *Wm, *v, *Wc, *Wld, *Wih_d, *Whh_d, *bih_d, *bhh_d,
              *Wproj, *bproj, *Wgate, *bgate;
  const int *mlen;
  float *ws;
  float *out;
};

__device__ __forceinline__ float ftanh(float x) {
  float e = __expf(2.f * x);
  return 1.f - 2.f / (e + 1.f);
}
__device__ __forceinline__ float fsig(float x) { return 1.f / (1.f + __expf(-x)); }

__device__ __forceinline__ unsigned f2bfbits(float x) {
  unsigned u = __builtin_bit_cast(unsigned, x);
  return (u + 0x7FFFu + ((u >> 16) & 1u)) >> 16;
}
__device__ __forceinline__ bf16x8_t packbf8(const float* f) {
  bf16x8_t r;
#pragma unroll
  for (int j = 0; j < 8; ++j) r[j] = (short)f2bfbits(f[j]);
  return r;
}
__device__ __forceinline__ bf16x8_t pack_from_f4(const float* src) {
  const float4* s4 = (const float4*)src;
  float4 lo = s4[0], hi = s4[1];
  float tmp[8] = {lo.x, lo.y, lo.z, lo.w, hi.x, hi.y, hi.z, hi.w};
  return packbf8(tmp);
}
__device__ __forceinline__ bf16x8_t ldbf8(const ushort_t* p) {
  return *(const bf16x8_t*)p;
}
#define MFMA16(a,b,c) __builtin_amdgcn_mfma_f32_16x16x32_bf16((a),(b),(c),0,0,0)

// ---- grid barrier: atomic-free flag barrier, relaxed spins, one fence pair ----
// arrive[bid*16] (64B-spaced), release at bar[4096]. Epoch increases monotonically.
__device__ __forceinline__ void gbar(int* bar, int ep) {
  __syncthreads();
  const int tid = threadIdx.x;
  int* release = bar + 4096;
  if (blockIdx.x == 0) {
    if (tid > 0 && tid < 256) {
      while (__hip_atomic_load(bar + tid * 16, __ATOMIC_RELAXED, __HIP_MEMORY_SCOPE_AGENT) < ep)
        __builtin_amdgcn_s_sleep(2);
    }
    __syncthreads();
    if (tid == 0) {
      // order: all arrival observations, then publish release (with our own wb)
      __builtin_amdgcn_fence(__ATOMIC_ACQUIRE, "agent");
      __hip_atomic_store(release, ep, __ATOMIC_RELEASE, __HIP_MEMORY_SCOPE_AGENT);
    }
    __syncthreads();
  } else {
    if (tid == 0) {
      __builtin_amdgcn_fence(__ATOMIC_RELEASE, "agent");  // writeback dirty L2
      __hip_atomic_store(bar + blockIdx.x * 16, ep, __ATOMIC_RELAXED, __HIP_MEMORY_SCOPE_AGENT);
      while (__hip_atomic_load(release, __ATOMIC_RELAXED, __HIP_MEMORY_SCOPE_AGENT) < ep)
        __builtin_amdgcn_s_sleep(2);
      __builtin_amdgcn_fence(__ATOMIC_ACQUIRE, "agent");  // invalidate stale L1/L2 once
    }
    __syncthreads();
  }
}

// ---------------- zero state ----------------
__global__ __launch_bounds__(256) void k_zero(Ptrs p) {
  unsigned i = blockIdx.x * 256 + threadIdx.x;
  if (i < ZERO_COUNT) p.ws[ZERO_BASE + i] = 0.f;
}

// ---------------- weight transposes for prenet ----------------
__global__ __launch_bounds__(256) void k_transpose(Ptrs p) {
  int i = blockIdx.x * 256 + threadIdx.x;
  if (i < 20480) {
    int m = i >> 8, c = i & 255;
    p.ws[F_W1T + i] = p.Wpre1[c * 80 + m];
  } else if (i < 20480 + 65536) {
    int j = i - 20480;
    int pp = j >> 8, q = j & 255;
    p.ws[F_W2T + j] = p.Wpre2[q * 256 + pp];
  }
}

// ---------------- prenet -> xsb (bf16) ----------------
__global__ __launch_bounds__(256) void k_prenet(Ptrs p) {
  __shared__ float dil[NBATCH * 80];
  __shared__ float h1[NBATCH * 256];
  const int t = blockIdx.x, tid = threadIdx.x;
  const float* W1T = p.ws + F_W1T;
  const float* W2T = p.ws + F_W2T;

  for (int i = tid; i < NBATCH * 80; i += 256) {
    int b = i / 80, m = i - b * 80;
    dil[i] = (t == 0) ? 0.f : p.dec_in[((size_t)b * 80 + m) * 400 + (t - 1)];
  }
  __syncthreads();

  float acc[NBATCH];
#pragma unroll
  for (int b = 0; b < NBATCH; ++b) acc[b] = 0.f;
  for (int m = 0; m < 80; ++m) {
    float w = W1T[m * 256 + tid];
#pragma unroll
    for (int b = 0; b < NBATCH; ++b) acc[b] = fmaf(dil[b * 80 + m], w, acc[b]);
  }
#pragma unroll
  for (int b = 0; b < NBATCH; ++b) h1[b * 256 + tid] = fmaxf(acc[b], 0.f);
  __syncthreads();

#pragma unroll
  for (int b = 0; b < NBATCH; ++b) acc[b] = 0.f;
  for (int q = 0; q < 256; ++q) {
    float w = W2T[q * 256 + tid];
#pragma unroll
    for (int b = 0; b < NBATCH; ++b) acc[b] = fmaf(h1[b * 256 + q], w, acc[b]);
  }
  ushort_t* xsbU = (ushort_t*)(p.ws + F_XSB);
#pragma unroll
  for (int b = 0; b < NBATCH; ++b)
    xsbU[((size_t)(t * NBATCH + b)) * 256 + tid] = (ushort_t)f2bfbits(fmaxf(acc[b], 0.f));
}

// ---------------- proc_mem fp32 ----------------
__global__ __launch_bounds__(256) void k_procmem(Ptrs p) {
  __shared__ alignas(16) float msl[16 * 512];
  const int b = blockIdx.x >> 4, s0 = (blockIdx.x & 15) << 4;
  const int tid = threadIdx.x;
  const float4* src = (const float4*)(p.memory + ((size_t)(b * SMEM + s0)) * 512);
  float4* dst = (float4*)msl;
  for (int i = tid; i < 16 * 512 / 4; i += 256) dst[i] = src[i];
  __syncthreads();

  const int a = tid & 127, sg = tid >> 7;
  const float4* wm = (const float4*)(p.Wm + (size_t)a * 512);
  float* pm = p.ws + F_PM;
  float acc[8];
#pragma unroll
  for (int j = 0; j < 8; ++j) acc[j] = 0.f;
  for (int k = 0; k < 128; ++k) {
    float4 w = wm[k];
#pragma unroll
    for (int j = 0; j < 8; ++j) {
      float4 m = ((const float4*)(msl + (size_t)(sg * 8 + j) * 512))[k];
      acc[j] += w.x * m.x + w.y * m.y + w.z * m.z + w.w * m.w;
    }
  }
#pragma unroll
  for (int j = 0; j < 8; ++j)
    pm[((size_t)(b * SMEM + s0 + sg * 8 + j)) * 128 + a] = acc[j];
}

// ---- pa (proc_att) MFMA task ----
__device__ __forceinline__ void wld_init(int pabase, const float* Wld, int m16, int kq, bf16x8_t* o) {
#pragma unroll
  for (int i = 0; i < 4; ++i) {
    int atile = (pabase + i) & 7;
    o[i] = pack_from_f4(Wld + ((size_t)(atile * 16 + m16)) * 32 + kq * 8);
  }
}
__device__ __forceinline__ void pa_do(int pabase, const bf16x8_t* wLd, int m16, int kq,
                                      const float* pmF, float* papmF, const ushort_t* locU) {
#pragma unroll
  for (int i = 0; i < 4; ++i) {
    int tau = pabase + i;
    int cb = tau >> 7, stile = (tau >> 3) & 15, atile = tau & 7;
    int scol = stile * 16 + m16;
    size_t rowo = ((size_t)cb * 256 + scol) * 128 + atile * 16 + kq * 4;
    f32x4_t acc = *(const f32x4_t*)(pmF + rowo);
    bf16x8_t bf = ldbf8(locU + ((size_t)cb * 256 + scol) * 32 + kq * 8);
    acc = MFMA16(wLd[i], bf, acc);
    *(f32x4_t*)(papmF + rowo) = acc;
  }
}

// ---------------- persistent scan: 256 blocks x 512 threads ----------------
__global__ __launch_bounds__(512, 2) void k_scan(Ptrs p) {
  __shared__ alignas(16) float sm[1536];
  const int bid = blockIdx.x, tid = threadIdx.x;
  const int wid = tid >> 6, lane = tid & 63;
  const int m16 = lane & 15, kq = lane >> 4;

  float* ws = p.ws;
  ushort_t* xsbU  = (ushort_t*)(ws + F_XSB);
  float*    pmF   = ws + F_PM;
  float*    papmF = ws + F_PAPM;
  ushort_t* locU  = (ushort_t*)(ws + F_LOC);
  ushort_t* ahbU  = (ushort_t*)(ws + F_AHB);
  ushort_t* dhbU  = (ushort_t*)(ws + F_DHB);
  ushort_t* ctxbU = (ushort_t*)(ws + F_CTXB);
  float*    ctxfF = ws + F_CTXF;
  float*    dhfF  = ws + F_DHF;
  int*      bar   = (int*)(ws + F_BAR);
  float* out_mel  = p.out;
  float* out_gate = p.out + 512000;
  float* out_al   = p.out + 518400;
  int ep = 0;

  if (bid < 64) {
    // ======== A-path: 8 waves = 4 strips x 2 K-halves ========
    const int ls = wid >> 1, half = wid & 1;
    const int strip = (bid << 2) | ls;                 // 0..255
    const int gA = m16 & 3, jA = m16 >> 2;
    const int wrowA = gA * 1024 + strip * 4 + jA;
    bf16x8_t wA[28];
#pragma unroll
    for (int c = 0; c < 28; ++c) {
      int k0 = (half * 28 + c) * 32 + kq * 8;
      const float* src = (k0 < 768) ? p.Wih_a + (size_t)wrowA * 768 + k0
                                    : p.Whh_a + (size_t)wrowA * 1024 + (k0 - 768);
      wA[c] = pack_from_f4(src);
    }
    const int nnA = strip * 4 + kq;
    float biasA[4];
#pragma unroll
    for (int r = 0; r < 4; ++r) biasA[r] = p.bih_a[r * 1024 + nnA] + p.bhh_a[r * 1024 + nnA];
    float acState = 0.f;
    __syncthreads();

    for (int t = 0; t <= TSTEPS; ++t) {
      // ---- PhX: A-LSTM step t ----
      const bool act = (t < TSTEPS);
      f32x4_t a0 = {0,0,0,0}, a1 = {0,0,0,0};
      if (act) {
        const ushort_t* xsrc = xsbU + ((size_t)t * 16 + m16) * 256;
        const ushort_t* csrc = ctxbU + (size_t)((t - 1) & 1) * 8192 + m16 * 512;
        const ushort_t* hsrc = ahbU + (size_t)((t - 1) & 1) * 16384 + m16 * 1024;
        if (half == 0) {
#pragma unroll
          for (int c = 0; c < 28; ++c) {
            const ushort_t* sp = (c < 8)  ? xsrc + c * 32 + kq * 8
                               : (c < 24) ? csrc + (c - 8) * 32 + kq * 8
                                          : hsrc + (c - 24) * 32 + kq * 8;
            bf16x8_t bf = ldbf8(sp);
            if (c & 1) a1 = MFMA16(wA[c], bf, a1); else a0 = MFMA16(wA[c], bf, a0);
          }
        } else {
#pragma unroll
          for (int c = 0; c < 28; ++c) {
            bf16x8_t bf = ldbf8(hsrc + (4 + c) * 32 + kq * 8);
            if (c & 1) a1 = MFMA16(wA[c], bf, a1); else a0 = MFMA16(wA[c], bf, a0);
          }
#pragma unroll
          for (int r = 0; r < 4; ++r) sm[((ls * 64 + lane) << 2) + r] = a0[r] + a1[r];
        }
      }
      __syncthreads();
      if (act && half == 0) {
        float z[4];
#pragma unroll
        for (int r = 0; r < 4; ++r)
          z[r] = a0[r] + a1[r] + sm[((ls * 64 + lane) << 2) + r] + biasA[r];
        float cn = fsig(z[1]) * acState + fsig(z[0]) * ftanh(z[2]);
        acState = cn;
        float h = fsig(z[3]) * ftanh(cn);
        ahbU[(size_t)(t & 1) * 16384 + m16 * 1024 + nnA] = (ushort_t)f2bfbits(h);
      }
      gbar(bar, ++ep);
      // ---- PhY: idle ----
      gbar(bar, ++ep);
    }
  } else if (bid < 192) {
    // ======== D-path: 8 waves = 2 strips x 4 K-quarters ========
    const int ls = wid >> 2, qt = wid & 3;
    const int strip = ((bid - 64) << 1) | ls;          // 0..255
    const int gD = m16 & 3, jD = m16 >> 2;
    const int wrowD = gD * 1024 + strip * 4 + jD;
    bf16x8_t wD[20];
#pragma unroll
    for (int c = 0; c < 20; ++c) {
      int k0 = (qt * 20 + c) * 32 + kq * 8;
      const float* src = (k0 < 1536) ? p.Wih_d + (size_t)wrowD * 1536 + k0
                                     : p.Whh_d + (size_t)wrowD * 1024 + (k0 - 1536);
      wD[c] = pack_from_f4(src);
    }
    const int nnD = strip * 4 + kq;
    float biasD[4];
#pragma unroll
    for (int r = 0; r < 4; ++r) biasD[r] = p.bih_d[r * 1024 + nnD] + p.bhh_d[r * 1024 + nnD];
    float dcState = 0.f;
    __syncthreads();

    for (int t = 0; t <= TSTEPS; ++t) {
      // ---- PhX: D-LSTM step t-1 ----
      const bool act = (t >= 1);
      f32x4_t a0 = {0,0,0,0}, a1 = {0,0,0,0};
      if (act) {
        const ushort_t* hsrc = ahbU + (size_t)((t - 1) & 1) * 16384 + m16 * 1024;
        const ushort_t* csrc = ctxbU + (size_t)((t - 1) & 1) * 8192 + m16 * 512;
        const ushort_t* dsrc = dhbU + (size_t)(t & 1) * 16384 + m16 * 1024;
#define DMFMA(SRC, OFF) { bf16x8_t bf = ldbf8((SRC) + (OFF) * 32 + kq * 8); \
          if (c & 1) a1 = MFMA16(wD[c], bf, a1); else a0 = MFMA16(wD[c], bf, a0); }
        if (qt == 0) {
#pragma unroll
          for (int c = 0; c < 20; ++c) DMFMA(hsrc, c)
        } else if (qt == 1) {
#pragma unroll
          for (int c = 0; c < 20; ++c) { if (c < 12) DMFMA(hsrc, 20 + c) else DMFMA(csrc, c - 12) }
        } else if (qt == 2) {
#pragma unroll
          for (int c = 0; c < 20; ++c) { if (c < 8) DMFMA(csrc, 8 + c) else DMFMA(dsrc, c - 8) }
        } else {
#pragma unroll
          for (int c = 0; c < 20; ++c) DMFMA(dsrc, 12 + c)
        }
#undef DMFMA
        if (qt != 0) {
#pragma unroll
          for (int r = 0; r < 4; ++r)
            sm[(((ls * 3 + qt - 1) * 64 + lane) << 2) + r] = a0[r] + a1[r];
        }
      }
      __syncthreads();
      if (act && qt == 0) {
        float z[4];
#pragma unroll
        for (int r = 0; r < 4; ++r) {
          z[r] = a0[r] + a1[r] + biasD[r];
#pragma unroll
          for (int j = 0; j < 3; ++j) z[r] += sm[(((ls * 3 + j) * 64 + lane) << 2) + r];
        }
        float cn = fsig(z[1]) * dcState + fsig(z[0]) * ftanh(z[2]);
        dcState = cn;
        float h = fsig(z[3]) * ftanh(cn);
        size_t po = (size_t)((t - 1) & 1) * 16384 + m16 * 1024 + nnD;
        dhbU[po] = (ushort_t)f2bfbits(h);
        dhfF[po] = h;
      }
      gbar(bar, ++ep);
      // ---- PhY: idle ----
      gbar(bar, ++ep);
    }
  } else if (bid < 208) {
    // ======== ATT path: block per batch; pa in PhX; att+ctx+conv in PhY ========
    const int b = bid - 192;
    const int pabase = ((bid - 192) * 8 + wid) * 4;
    bf16x8_t wLd[4];
    wld_init(pabase, p.Wld, m16, kq, wLd);
    // Wq frags: wave wid covers a-rows [wid*16, wid*16+16)
    bf16x8_t wq[32];
#pragma unroll
    for (int c = 0; c < 32; ++c)
      wq[c] = pack_from_f4(p.Wq + (size_t)(wid * 16 + m16) * 1024 + c * 32 + kq * 8);
    // conv weight frags (both filter halves; k2 = ch*31+k padded to 64)
    bf16x8_t wC[2][2];
#pragma unroll
    for (int ft = 0; ft < 2; ++ft)
#pragma unroll
      for (int ck = 0; ck < 2; ++ck) {
        float tmp[8];
#pragma unroll
        for (int jj = 0; jj < 8; ++jj) {
          int k2 = ck * 32 + kq * 8 + jj;
          float vv = 0.f;
          if (k2 < 62) { int ch = (k2 < 31) ? 0 : 1; int k = k2 - 31 * ch;
            vv = p.Wc[((size_t)(ft * 16 + m16) * 2 + ch) * 31 + k]; }
          tmp[jj] = vv;
        }
        wC[ft][ck] = packbf8(tmp);
      }
    float* qsm  = sm;          // 128
    float* red  = sm + 128;    // 16
    float* vsm  = sm + 144;    // 128
    float* smaw = sm + 272;    // 256
    float* smawc= sm + 528;    // 256
    if (tid < 128) vsm[tid] = p.v[tid];
    if (tid < 256) smawc[tid] = 0.f;
    const int mlenb = p.mlen[b];
    const int s = tid >> 1, ha = tid & 1;
    __syncthreads();

    for (int t = 0; t <= TSTEPS; ++t) {
      // ---- PhX: pa duty ----
      if (t < TSTEPS) pa_do(pabase, wLd, m16, kq, pmF, papmF, locU);
      gbar(bar, ++ep);
      // ---- PhY: attention ----
      if (t < TSTEPS) {
        // q = Wq @ ah(t)
        {
          f32x4_t acc = {0,0,0,0};
#pragma unroll
          for (int c = 0; c < 32; ++c) {
            bf16x8_t bf = ldbf8(ahbU + (size_t)(t & 1) * 16384 + m16 * 1024 + c * 32 + kq * 8);
            acc = MFMA16(wq[c], bf, acc);
          }
          if (m16 == b) {
#pragma unroll
            for (int r = 0; r < 4; ++r) qsm[wid * 16 + kq * 4 + r] = acc[r];
          }
        }
        __syncthreads();
        // e[s] = v . tanh(q + papm), 2 threads per s
        float e;
        {
          const float* pr = papmF + ((size_t)b * 256 + s) * 128 + ha * 64;
          const float* qq = qsm + ha * 64;
          const float* vv = vsm + ha * 64;
          float acc = 0.f;
#pragma unroll
          for (int kk = 0; kk < 16; ++kk) {
            f32x4_t pz = *(const f32x4_t*)(pr + kk * 4);
            f32x4_t q4 = *(const f32x4_t*)(qq + kk * 4);
            f32x4_t v4 = *(const f32x4_t*)(vv + kk * 4);
            acc = fmaf(v4[0], ftanh(q4[0] + pz[0]), acc);
            acc = fmaf(v4[1], ftanh(q4[1] + pz[1]), acc);
            acc = fmaf(v4[2], ftanh(q4[2] + pz[2]), acc);
            acc = fmaf(v4[3], ftanh(q4[3] + pz[3]), acc);
          }
          acc += __shfl_xor(acc, 1);
          e = (s >= mlenb) ? -1.0e9f : acc;
        }
        // softmax over 256 s (each duplicated x2; odd threads contribute 0 to sum)
        float mv = e;
        for (int o = 32; o; o >>= 1) mv = fmaxf(mv, __shfl_xor(mv, o));
        if (lane == 0) red[wid] = mv;
        __syncthreads();
        float gmax = red[0];
#pragma unroll
        for (int w = 1; w < 8; ++w) gmax = fmaxf(gmax, red[w]);
        float pv = (ha == 0) ? __expf(e - gmax) : 0.f;
        float sv = pv;
        for (int o = 32; o; o >>= 1) sv += __shfl_xor(sv, o);
        if (lane == 0) red[8 + wid] = sv;
        __syncthreads();
        float gsum = 0.f;
#pragma unroll
        for (int w = 0; w < 8; ++w) gsum += red[8 + w];
        if (ha == 0) {
          float awv = pv / gsum;
          smaw[s] = awv;
          smawc[s] += awv;
          out_al[((size_t)b * 400 + t) * 256 + s] = awv;
        }
        __syncthreads();
        // ctx(t) = sum_s aw[s] * memory[b][s][:]
        {
          float acc = 0.f;
          const float* mb = p.memory + (size_t)b * 256 * 512 + tid;
#pragma unroll 8
          for (int ss = 0; ss < 256; ++ss) acc = fmaf(smaw[ss], mb[(size_t)ss * 512], acc);
          ctxfF[(size_t)(t & 1) * 8192 + b * 512 + tid] = acc;
          ctxbU[(size_t)(t & 1) * 8192 + b * 512 + tid] = (ushort_t)f2bfbits(acc);
        }
        // conv(t+1) from LDS aw/awc: 4 (stile,ft) tasks per wave
#pragma unroll
        for (int u = 0; u < 4; ++u) {
          int task = wid * 4 + u;            // 0..31
          int stile = task >> 1, ft = task & 1;
          int scol = stile * 16 + m16;
          f32x4_t acc = {0,0,0,0};
#pragma unroll
          for (int ck = 0; ck < 2; ++ck) {
            float tmp[8];
#pragma unroll
            for (int jj = 0; jj < 8; ++jj) {
              int k2 = ck * 32 + kq * 8 + jj;
              float vv = 0.f;
              if (k2 < 62) {
                int ch = (k2 < 31) ? 0 : 1; int k = k2 - 31 * ch;
                int sp = scol + k - 15;
                if (sp >= 0 && sp < 256) vv = (ch ? smawc : smaw)[sp];
              }
              tmp[jj] = vv;
            }
            acc = MFMA16(wC[ft][ck], packbf8(tmp), acc);
          }
#pragma unroll
          for (int r = 0; r < 4; ++r)
            locU[((size_t)b * 256 + scol) * 32 + ft * 16 + kq * 4 + r] = (ushort_t)f2bfbits(acc[r]);
        }
      }
      gbar(bar, ++ep);
    }
  } else if (bid < 216) {
    // ======== PROJ path: 8 blocks; pa in PhX; projection in PhY ========
    const int pabase = ((bid - 192) * 8 + wid) * 4;
    bf16x8_t wLd[4];
    wld_init(pabase, p.Wld, m16, kq, wLd);
    const int wv = (bid - 208) * 8 + wid;   // 0..63
    int rows[2] = {wv * 2, wv * 2 + 1};
    float wreg[2][24], biasr[2];
#pragma unroll
    for (int rr = 0; rr < 2; ++rr) {
      int row = rows[rr];
      biasr[rr] = 0.f;
#pragma unroll
      for (int j = 0; j < 24; ++j) wreg[rr][j] = 0.f;
      if (row < 80) {
#pragma unroll
        for (int j = 0; j < 24; ++j) wreg[rr][j] = p.Wproj[(size_t)row * 1536 + lane + 64 * j];
        biasr[rr] = p.bproj[row];
      } else if (row == 80) {
#pragma unroll
        for (int j = 0; j < 24; ++j) wreg[rr][j] = p.Wgate[lane + 64 * j];
        biasr[rr] = p.bgate[0];
      }
    }
    __syncthreads();
    for (int t = 0; t <= TSTEPS; ++t) {
      if (t < TSTEPS) pa_do(pabase, wLd, m16, kq, pmF, papmF, locU);
      gbar(bar, ++ep);
      // ---- PhY: projection for step t-1 ----
      if (t >= 1 && wv <= 40) {
        const size_t pp = (size_t)((t - 1) & 1) * 16384;
        const size_t pc = (size_t)((t - 1) & 1) * 8192;
        for (int b2 = 0; b2 < 16; ++b2) {
          float h[24];
#pragma unroll
          for (int j = 0; j < 24; ++j)
            h[j] = (j < 16) ? dhfF[pp + b2 * 1024 + lane + 64 * j]
                            : ctxfF[pc + b2 * 512 + lane + 64 * (j - 16)];
#pragma unroll
          for (int rr = 0; rr < 2; ++rr) {
            if (rows[rr] > 80) continue;
            float d = 0.f;
#pragma unroll
            for (int j = 0; j < 24; ++j) d = fmaf(wreg[rr][j], h[j], d);
            for (int o = 32; o; o >>= 1) d += __shfl_xor(d, o);
            if (lane == 0) {
              d += biasr[rr];
              if (rows[rr] < 80) out_mel[((size_t)b2 * 80 + rows[rr]) * 400 + (t - 1)] = d;
              else out_gate[(size_t)b2 * 400 + (t - 1)] = d;
            }
          }
        }
      }
      gbar(bar, ++ep);
    }
  } else {
    // ======== PA-only path ========
    const int pabase = ((bid - 192) * 8 + wid) * 4;
    bf16x8_t wLd[4];
    wld_init(pabase, p.Wld, m16, kq, wLd);
    __syncthreads();
    for (int t = 0; t <= TSTEPS; ++t) {
      if (t < TSTEPS) pa_do(pabase, wLd, m16, kq, pmF, papmF, locU);
      gbar(bar, ++ep);
      gbar(bar, ++ep);
    }
  }
}

extern "C" void kernel_launch(void* const* d_in, const int* in_sizes, int n_in,
                              void* d_out, int out_size, void* d_ws, size_t ws_size,
                              hipStream_t stream) {
  (void)in_sizes; (void)n_in; (void)out_size; (void)ws_size;
  Ptrs p;
  p.memory = (const float*)d_in[0];
  p.dec_in = (const float*)d_in[1];
  p.Wpre1  = (const float*)d_in[2];
  p.Wpre2  = (const float*)d_in[3];
  p.Wih_a  = (const float*)d_in[4];
  p.Whh_a  = (const float*)d_in[5];
  p.bih_a  = (const float*)d_in[6];
  p.bhh_a  = (const float*)d_in[7];
  p.Wq     = (const float*)d_in[8];
  p.Wm     = (const float*)d_in[9];
  p.v      = (const float*)d_in[10];
  p.Wc     = (const float*)d_in[11];
  p.Wld    = (const float*)d_in[12];
  p.Wih_d  = (const float*)d_in[13];
  p.Whh_d  = (const float*)d_in[14];
  p.bih_d  = (const float*)d_in[15];
  p.bhh_d  = (const float*)d_in[16];
  p.Wproj  = (const float*)d_in[17];
  p.bproj  = (const float*)d_in[18];
  p.Wgate  = (const float*)d_in[19];
  p.bgate  = (const float*)d_in[20];
  p.mlen   = (const int*)d_in[21];
  p.ws  = (float*)d_ws;
  p.out = (float*)d_out;

  hipLaunchKernelGGL(k_zero,      dim3((ZERO_COUNT + 255) / 256), dim3(256), 0, stream, p);
  hipLaunchKernelGGL(k_transpose, dim3(336), dim3(256), 0, stream, p);
  hipLaunchKernelGGL(k_prenet,    dim3(400), dim3(256), 0, stream, p);
  hipLaunchKernelGGL(k_procmem,   dim3(256), dim3(256), 0, stream, p);

  void* kargs[] = { (void*)&p };
  hipError_t err = hipLaunchCooperativeKernel(reinterpret_cast<const void*>(&k_scan),
                                              dim3(256), dim3(512), kargs, 0, stream);
  if (err != hipSuccess) {
    (void)hipGetLastError();
    hipLaunchKernelGGL(k_scan, dim3(256), dim3(512), 0, stream, p);
  }
}

// Round 5
// 16945.912 us; speedup vs baseline: 7.9440x; 1.0602x over previous
//
#include <hip/hip_runtime.h>

typedef unsigned short ushort_t;
typedef float f32x4_t __attribute__((ext_vector_type(4)));
typedef short bf16x8_t __attribute__((ext_vector_type(8)));

// ---- problem constants ----
#define NBATCH 16
#define SMEM   256
#define TSTEPS 400

// ---- workspace layout (float offsets) ----
#define F_XSB   0u         // 400*16*256 bf16 = 819200 floats
#define F_PM    819200u    // 16*256*128 f32 = 524288
#define F_MMIX  1343488u   // 16*81*256 f32 = 331776  (M_b = Wctx . mem^T)
#define F_W1T   1675264u   // 20480
#define F_W2T   1695744u   // 65536
// ---- zeroed region ----
#define F_AHB   1761280u   // 2*16*1024 bf16 = 16384 floats
#define F_DHB   1777664u   // 16384
#define F_CTXB  1794048u   // 2*16*512 bf16 = 8192 floats
#define F_DHF   1802240u   // 2*16*1024 f32 = 32768
#define F_EEX   1835008u   // 16*256 f32 (e exchange)
#define F_BAR   1839104u   // 256*16 ints
#define F_EFL   1843200u   // 64*16 ints (e-flags)
#define F_AWF   1844224u   // 32*16 ints (aw-flags)
#define ZERO_BASE  F_AHB
#define ZERO_COUNT 83456u
// total ~1844736 floats = 7.4 MB

struct Ptrs {
  const float *memory, *dec_in, *Wpre1, *Wpre2, *Wih_a, *Whh_a, *bih_a, *bhh_a,
              *Wq, *Wm, *v, *Wc, *Wld, *Wih_d, *Whh_d, *bih_d, *bhh_d,
              *Wproj, *bproj, *Wgate, *bgate;
  const int *mlen;
  float *ws;
  float *out;
};

__device__ __forceinline__ float ftanh(float x) {
  float e = __expf(2.f * x);
  return 1.f - 2.f / (e + 1.f);
}
__device__ __forceinline__ float fsig(float x) { return 1.f / (1.f + __expf(-x)); }

__device__ __forceinline__ unsigned f2bfbits(float x) {
  unsigned u = __builtin_bit_cast(unsigned, x);
  return (u + 0x7FFFu + ((u >> 16) & 1u)) >> 16;
}
__device__ __forceinline__ float bf2f(ushort_t u) {
  unsigned v = ((unsigned)u) << 16;
  return __builtin_bit_cast(float, v);
}
__device__ __forceinline__ bf16x8_t packbf8(const float* f) {
  bf16x8_t r;
#pragma unroll
  for (int j = 0; j < 8; ++j) r[j] = (short)f2bfbits(f[j]);
  return r;
}
__device__ __forceinline__ bf16x8_t pack_from_f4(const float* src) {
  const float4* s4 = (const float4*)src;
  float4 lo = s4[0], hi = s4[1];
  float tmp[8] = {lo.x, lo.y, lo.z, lo.w, hi.x, hi.y, hi.z, hi.w};
  return packbf8(tmp);
}
__device__ __forceinline__ bf16x8_t ldbf8(const ushort_t* p) {
  return *(const bf16x8_t*)p;
}
#define MFMA16(a,b,c) __builtin_amdgcn_mfma_f32_16x16x32_bf16((a),(b),(c),0,0,0)

// ---- grid barrier: all-poll-all flag barrier ----
__device__ __forceinline__ void gbar(int* bar, int ep) {
  __syncthreads();
  if (threadIdx.x == 0) {
    __builtin_amdgcn_fence(__ATOMIC_RELEASE, "agent");
    __hip_atomic_store(bar + blockIdx.x * 16, ep, __ATOMIC_RELAXED, __HIP_MEMORY_SCOPE_AGENT);
  }
  __syncthreads();
  if (threadIdx.x < 256) {
    while (__hip_atomic_load(bar + threadIdx.x * 16, __ATOMIC_RELAXED, __HIP_MEMORY_SCOPE_AGENT) < ep)
      __builtin_amdgcn_s_sleep(1);
  }
  __syncthreads();
  if (threadIdx.x == 0) __builtin_amdgcn_fence(__ATOMIC_ACQUIRE, "agent");
  __syncthreads();
}

// ---------------- zero state ----------------
__global__ __launch_bounds__(256) void k_zero(Ptrs p) {
  unsigned i = blockIdx.x * 256 + threadIdx.x;
  if (i < ZERO_COUNT) p.ws[ZERO_BASE + i] = 0.f;
}

// ---------------- weight transposes for prenet ----------------
__global__ __launch_bounds__(256) void k_transpose(Ptrs p) {
  int i = blockIdx.x * 256 + threadIdx.x;
  if (i < 20480) {
    int m = i >> 8, c = i & 255;
    p.ws[F_W1T + i] = p.Wpre1[c * 80 + m];
  } else if (i < 20480 + 65536) {
    int j = i - 20480;
    int pp = j >> 8, q = j & 255;
    p.ws[F_W2T + j] = p.Wpre2[q * 256 + pp];
  }
}

// ---------------- prenet -> xsb (bf16) ----------------
__global__ __launch_bounds__(256) void k_prenet(Ptrs p) {
  __shared__ float dil[NBATCH * 80];
  __shared__ float h1[NBATCH * 256];
  const int t = blockIdx.x, tid = threadIdx.x;
  const float* W1T = p.ws + F_W1T;
  const float* W2T = p.ws + F_W2T;

  for (int i = tid; i < NBATCH * 80; i += 256) {
    int b = i / 80, m = i - b * 80;
    dil[i] = (t == 0) ? 0.f : p.dec_in[((size_t)b * 80 + m) * 400 + (t - 1)];
  }
  __syncthreads();

  float acc[NBATCH];
#pragma unroll
  for (int b = 0; b < NBATCH; ++b) acc[b] = 0.f;
  for (int m = 0; m < 80; ++m) {
    float w = W1T[m * 256 + tid];
#pragma unroll
    for (int b = 0; b < NBATCH; ++b) acc[b] = fmaf(dil[b * 80 + m], w, acc[b]);
  }
#pragma unroll
  for (int b = 0; b < NBATCH; ++b) h1[b * 256 + tid] = fmaxf(acc[b], 0.f);
  __syncthreads();

#pragma unroll
  for (int b = 0; b < NBATCH; ++b) acc[b] = 0.f;
  for (int q = 0; q < 256; ++q) {
    float w = W2T[q * 256 + tid];
#pragma unroll
    for (int b = 0; b < NBATCH; ++b) acc[b] = fmaf(h1[b * 256 + q], w, acc[b]);
  }
  ushort_t* xsbU = (ushort_t*)(p.ws + F_XSB);
#pragma unroll
  for (int b = 0; b < NBATCH; ++b)
    xsbU[((size_t)(t * NBATCH + b)) * 256 + tid] = (ushort_t)f2bfbits(fmaxf(acc[b], 0.f));
}

// ---------------- proc_mem fp32 ----------------
__global__ __launch_bounds__(256) void k_procmem(Ptrs p) {
  __shared__ alignas(16) float msl[16 * 512];
  const int b = blockIdx.x >> 4, s0 = (blockIdx.x & 15) << 4;
  const int tid = threadIdx.x;
  const float4* src = (const float4*)(p.memory + ((size_t)(b * SMEM + s0)) * 512);
  float4* dst = (float4*)msl;
  for (int i = tid; i < 16 * 512 / 4; i += 256) dst[i] = src[i];
  __syncthreads();

  const int a = tid & 127, sg = tid >> 7;
  const float4* wm = (const float4*)(p.Wm + (size_t)a * 512);
  float* pm = p.ws + F_PM;
  float acc[8];
#pragma unroll
  for (int j = 0; j < 8; ++j) acc[j] = 0.f;
  for (int k = 0; k < 128; ++k) {
    float4 w = wm[k];
#pragma unroll
    for (int j = 0; j < 8; ++j) {
      float4 m = ((const float4*)(msl + (size_t)(sg * 8 + j) * 512))[k];
      acc[j] += w.x * m.x + w.y * m.y + w.z * m.z + w.w * m.w;
    }
  }
#pragma unroll
  for (int j = 0; j < 8; ++j)
    pm[((size_t)(b * SMEM + s0 + sg * 8 + j)) * 128 + a] = acc[j];
}

// ---------------- premix: M[b][row][s] = Wctx[row][:] . memory[b][s][:] ----------------
__global__ __launch_bounds__(512) void k_premix(Ptrs p) {
  const int b = blockIdx.x, tid = threadIdx.x;
  float* M = p.ws + F_MMIX;
  for (int i = tid; i < 81 * 256; i += 512) {
    int row = i >> 8, s = i & 255;
    const float* wrow = (row < 80) ? p.Wproj + (size_t)row * 1536 + 1024 : p.Wgate + 1024;
    const float4* w4 = (const float4*)wrow;
    const float4* m4 = (const float4*)(p.memory + ((size_t)(b * 256 + s)) * 512);
    float acc = 0.f;
#pragma unroll 4
    for (int k = 0; k < 128; ++k) {
      float4 w = w4[k], m = m4[k];
      acc += w.x * m.x + w.y * m.y + w.z * m.z + w.w * m.w;
    }
    M[((size_t)b * 81 + row) * 256 + s] = acc;
  }
}

// ---------------- persistent scan: 256 blocks x 512 threads ----------------
__global__ __launch_bounds__(512, 2) void k_scan(Ptrs p) {
  __shared__ alignas(16) float sm[12288];   // 48 KB
  const int bid = blockIdx.x, tid = threadIdx.x;
  const int wid = tid >> 6, lane = tid & 63;
  const int m16 = lane & 15, kq = lane >> 4;

  float* ws = p.ws;
  ushort_t* xsbU  = (ushort_t*)(ws + F_XSB);
  float*    pmF   = ws + F_PM;
  float*    Mx    = ws + F_MMIX;
  ushort_t* ahbU  = (ushort_t*)(ws + F_AHB);
  ushort_t* dhbU  = (ushort_t*)(ws + F_DHB);
  ushort_t* ctxbU = (ushort_t*)(ws + F_CTXB);
  float*    dhfF  = ws + F_DHF;
  float*    eexG  = ws + F_EEX;
  int*      bar   = (int*)(ws + F_BAR);
  int*      eflag = (int*)(ws + F_EFL);
  int*      awfl  = (int*)(ws + F_AWF);
  float* out_mel  = p.out;
  float* out_gate = p.out + 512000;
  float* out_al   = p.out + 518400;
  int ep = 0;

  if (bid < 64) {
    // ======== A-path: PhX = A-LSTM(t). 8 waves = 4 strips x 2 K-halves ========
    const int ls = wid >> 1, half = wid & 1;
    const int strip = (bid << 2) | ls;
    const int gA = m16 & 3, jA = m16 >> 2;
    const int wrowA = gA * 1024 + strip * 4 + jA;
    bf16x8_t wA[28];
#pragma unroll
    for (int c = 0; c < 28; ++c) {
      int k0 = (half * 28 + c) * 32 + kq * 8;
      const float* src = (k0 < 768) ? p.Wih_a + (size_t)wrowA * 768 + k0
                                    : p.Whh_a + (size_t)wrowA * 1024 + (k0 - 768);
      wA[c] = pack_from_f4(src);
    }
    const int nnA = strip * 4 + kq;
    float biasA[4];
#pragma unroll
    for (int r = 0; r < 4; ++r) biasA[r] = p.bih_a[r * 1024 + nnA] + p.bhh_a[r * 1024 + nnA];
    float acState = 0.f;
    __syncthreads();

    for (int t = 0; t <= TSTEPS; ++t) {
      const bool act = (t < TSTEPS);
      f32x4_t a0 = {0,0,0,0}, a1 = {0,0,0,0};
      if (act) {
        const ushort_t* xsrc = xsbU + ((size_t)t * 16 + m16) * 256;
        const ushort_t* csrc = ctxbU + (size_t)((t - 1) & 1) * 8192 + m16 * 512;
        const ushort_t* hsrc = ahbU + (size_t)((t - 1) & 1) * 16384 + m16 * 1024;
        if (half == 0) {
#pragma unroll
          for (int c = 0; c < 28; ++c) {
            const ushort_t* sp = (c < 8)  ? xsrc + c * 32 + kq * 8
                               : (c < 24) ? csrc + (c - 8) * 32 + kq * 8
                                          : hsrc + (c - 24) * 32 + kq * 8;
            bf16x8_t bf = ldbf8(sp);
            if (c & 1) a1 = MFMA16(wA[c], bf, a1); else a0 = MFMA16(wA[c], bf, a0);
          }
        } else {
#pragma unroll
          for (int c = 0; c < 28; ++c) {
            bf16x8_t bf = ldbf8(hsrc + (4 + c) * 32 + kq * 8);
            if (c & 1) a1 = MFMA16(wA[c], bf, a1); else a0 = MFMA16(wA[c], bf, a0);
          }
#pragma unroll
          for (int r = 0; r < 4; ++r) sm[((ls * 64 + lane) << 2) + r] = a0[r] + a1[r];
        }
      }
      __syncthreads();
      if (act && half == 0) {
        float z[4];
#pragma unroll
        for (int r = 0; r < 4; ++r)
          z[r] = a0[r] + a1[r] + sm[((ls * 64 + lane) << 2) + r] + biasA[r];
        float cn = fsig(z[1]) * acState + fsig(z[0]) * ftanh(z[2]);
        acState = cn;
        float h = fsig(z[3]) * ftanh(cn);
        ahbU[(size_t)(t & 1) * 16384 + m16 * 1024 + nnA] = (ushort_t)f2bfbits(h);
      }
      gbar(bar, ++ep);
      // PhY idle
      gbar(bar, ++ep);
    }
  } else if (bid < 192) {
    // ======== D-path: PhX = D-LSTM(t-1); PhY = ctx slice ========
    const int ls = wid >> 2, qt = wid & 3;
    const int strip = ((bid - 64) << 1) | ls;
    const int gD = m16 & 3, jD = m16 >> 2;
    const int wrowD = gD * 1024 + strip * 4 + jD;
    bf16x8_t wD[20];
#pragma unroll
    for (int c = 0; c < 20; ++c) {
      int k0 = (qt * 20 + c) * 32 + kq * 8;
      const float* src = (k0 < 1536) ? p.Wih_d + (size_t)wrowD * 1536 + k0
                                     : p.Whh_d + (size_t)wrowD * 1024 + (k0 - 1536);
      wD[c] = pack_from_f4(src);
    }
    const int nnD = strip * 4 + kq;
    float biasD[4];
#pragma unroll
    for (int r = 0; r < 4; ++r) biasD[r] = p.bih_d[r * 1024 + nnD] + p.bhh_d[r * 1024 + nnD];
    float dcState = 0.f;

    // ctx duty: batch cb, 64-col slice sl; memory slice -> LDS bf16 (32 KB)
    const int cb = (bid - 64) >> 3, sl = (bid - 64) & 7;
    float* awsm = sm + 1280;
    float* part = sm + 1536;
    ushort_t* memu = (ushort_t*)(sm + 2048);
    for (int i = tid; i < 16384; i += 512) {
      int s = i >> 6, c = i & 63;
      memu[i] = (ushort_t)f2bfbits(p.memory[((size_t)cb * 256 + s) * 512 + sl * 64 + c]);
    }
    __syncthreads();

    for (int t = 0; t <= TSTEPS; ++t) {
      // ---- PhX: D-LSTM(t-1) ----
      const bool act = (t >= 1);
      f32x4_t a0 = {0,0,0,0}, a1 = {0,0,0,0};
      if (act) {
        const ushort_t* hsrc = ahbU + (size_t)((t - 1) & 1) * 16384 + m16 * 1024;
        const ushort_t* csrc = ctxbU + (size_t)((t - 1) & 1) * 8192 + m16 * 512;
        const ushort_t* dsrc = dhbU + (size_t)(t & 1) * 16384 + m16 * 1024;
#define DMFMA(SRC, OFF) { bf16x8_t bf = ldbf8((SRC) + (OFF) * 32 + kq * 8); \
          if (c & 1) a1 = MFMA16(wD[c], bf, a1); else a0 = MFMA16(wD[c], bf, a0); }
        if (qt == 0) {
#pragma unroll
          for (int c = 0; c < 20; ++c) DMFMA(hsrc, c)
        } else if (qt == 1) {
#pragma unroll
          for (int c = 0; c < 20; ++c) { if (c < 12) DMFMA(hsrc, 20 + c) else DMFMA(csrc, c - 12) }
        } else if (qt == 2) {
#pragma unroll
          for (int c = 0; c < 20; ++c) { if (c < 8) DMFMA(csrc, 8 + c) else DMFMA(dsrc, c - 8) }
        } else {
#pragma unroll
          for (int c = 0; c < 20; ++c) DMFMA(dsrc, 12 + c)
        }
#undef DMFMA
        if (qt != 0) {
#pragma unroll
          for (int r = 0; r < 4; ++r)
            sm[(((ls * 3 + qt - 1) * 64 + lane) << 2) + r] = a0[r] + a1[r];
        }
      }
      __syncthreads();
      if (act && qt == 0) {
        float z[4];
#pragma unroll
        for (int r = 0; r < 4; ++r) {
          z[r] = a0[r] + a1[r] + biasD[r];
#pragma unroll
          for (int j = 0; j < 3; ++j) z[r] += sm[(((ls * 3 + j) * 64 + lane) << 2) + r];
        }
        float cn = fsig(z[1]) * dcState + fsig(z[0]) * ftanh(z[2]);
        dcState = cn;
        float h = fsig(z[3]) * ftanh(cn);
        size_t po = (size_t)((t - 1) & 1) * 16384 + m16 * 1024 + nnD;
        dhbU[po] = (ushort_t)f2bfbits(h);
        dhfF[po] = h;
      }
      gbar(bar, ++ep);
      // ---- PhY: ctx(t) after aw flags ----
      if (t < TSTEPS) {
        if (tid == 0) {
          while (__hip_atomic_load(awfl + (cb * 2) * 16, __ATOMIC_RELAXED, __HIP_MEMORY_SCOPE_AGENT) < t + 1)
            __builtin_amdgcn_s_sleep(1);
          while (__hip_atomic_load(awfl + (cb * 2 + 1) * 16, __ATOMIC_RELAXED, __HIP_MEMORY_SCOPE_AGENT) < t + 1)
            __builtin_amdgcn_s_sleep(1);
          __builtin_amdgcn_fence(__ATOMIC_ACQUIRE, "agent");
        }
        __syncthreads();
        if (tid < 256) awsm[tid] = out_al[((size_t)cb * 400 + t) * 256 + tid];
        __syncthreads();
        const int c = tid & 63, sg = tid >> 6;
        float acc = 0.f;
#pragma unroll 8
        for (int si = 0; si < 32; ++si) {
          int s = sg * 32 + si;
          acc = fmaf(awsm[s], bf2f(memu[s * 64 + c]), acc);
        }
        part[sg * 64 + c] = acc;
        __syncthreads();
        if (tid < 64) {
          float v = 0.f;
#pragma unroll
          for (int j = 0; j < 8; ++j) v += part[j * 64 + tid];
          ctxbU[(size_t)(t & 1) * 8192 + cb * 512 + sl * 64 + tid] = (ushort_t)f2bfbits(v);
        }
      }
      gbar(bar, ++ep);
    }
  } else if (bid < 224) {
    // ======== ATT path: 2 blocks per batch ========
    const int b = (bid - 192) >> 1, sh = (bid - 192) & 1;
    const int s0 = sh << 7;
    const int mlenb = p.mlen[b];
    ushort_t* pmu  = (ushort_t*)sm;              // 128x128 bf16
    ushort_t* locu = (ushort_t*)(sm + 8192);     // 128x32 bf16
    float* qsm   = sm + 10240;
    float* vsm   = sm + 10368;
    float* esm   = sm + 10496;
    float* red   = sm + 10752;
    float* smaw  = sm + 10768;
    float* smawc = sm + 11024;

    // Wq frags: wave wid covers a-rows [wid*16, wid*16+16)
    bf16x8_t wq[32];
#pragma unroll
    for (int c = 0; c < 32; ++c)
      wq[c] = pack_from_f4(p.Wq + (size_t)(wid * 16 + m16) * 1024 + c * 32 + kq * 8);
    // Wld frags: all 8 a-tiles
    bf16x8_t wLd[8];
#pragma unroll
    for (int at = 0; at < 8; ++at)
      wLd[at] = pack_from_f4(p.Wld + ((size_t)(at * 16 + m16)) * 32 + kq * 8);
    // conv weight frags
    bf16x8_t wC[2][2];
#pragma unroll
    for (int ft = 0; ft < 2; ++ft)
#pragma unroll
      for (int ck = 0; ck < 2; ++ck) {
        float tmp[8];
#pragma unroll
        for (int jj = 0; jj < 8; ++jj) {
          int k2 = ck * 32 + kq * 8 + jj;
          float vv = 0.f;
          if (k2 < 62) { int ch = (k2 < 31) ? 0 : 1; int k = k2 - 31 * ch;
            vv = p.Wc[((size_t)(ft * 16 + m16) * 2 + ch) * 31 + k]; }
          tmp[jj] = vv;
        }
        wC[ft][ck] = packbf8(tmp);
      }
    // preload pm half as bf16; init aw/awc
    for (int i = tid; i < 16384; i += 512) {
      int sloc = i >> 7, a = i & 127;
      pmu[i] = (ushort_t)f2bfbits(pmF[((size_t)(b * 256 + s0 + sloc)) * 128 + a]);
    }
    if (tid < 128) vsm[tid] = p.v[tid];
    if (tid < 256) { smaw[tid] = 0.f; smawc[tid] = 0.f; }
    __syncthreads();

    for (int t = 0; t <= TSTEPS; ++t) {
      // PhX idle
      gbar(bar, ++ep);
      // ---- PhY: conv -> q -> pa+e -> exchange -> softmax -> aw ----
      if (t < TSTEPS) {
        // conv(t): 2 tasks per wave, local s-half
#pragma unroll
        for (int u = 0; u < 2; ++u) {
          int task = wid * 2 + u;
          int stile = task >> 1, ft = task & 1;
          int scol_l = stile * 16 + m16;
          int scol_g = s0 + scol_l;
          f32x4_t acc = {0,0,0,0};
#pragma unroll
          for (int ck = 0; ck < 2; ++ck) {
            float tmp[8];
#pragma unroll
            for (int jj = 0; jj < 8; ++jj) {
              int k2 = ck * 32 + kq * 8 + jj;
              float vv = 0.f;
              if (k2 < 62) {
                int ch = (k2 < 31) ? 0 : 1; int k = k2 - 31 * ch;
                int sp = scol_g + k - 15;
                if (sp >= 0 && sp < 256) vv = (ch ? smawc : smaw)[sp];
              }
              tmp[jj] = vv;
            }
            acc = MFMA16(wC[ft][ck], packbf8(tmp), acc);
          }
#pragma unroll
          for (int r = 0; r < 4; ++r)
            locu[scol_l * 32 + ft * 16 + kq * 4 + r] = (ushort_t)f2bfbits(acc[r]);
        }
        // q(t) = Wq . ah(t)
        {
          f32x4_t acc = {0,0,0,0};
#pragma unroll
          for (int c = 0; c < 32; ++c) {
            bf16x8_t bf = ldbf8(ahbU + (size_t)(t & 1) * 16384 + m16 * 1024 + c * 32 + kq * 8);
            acc = MFMA16(wq[c], bf, acc);
          }
          if (m16 == b) {
#pragma unroll
            for (int r = 0; r < 4; ++r) qsm[wid * 16 + kq * 4 + r] = acc[r];
          }
        }
        __syncthreads();
        // fused pa + e: wave wid handles local s-tile wid
        {
          const int sloc = wid * 16 + m16;
          const int sglob = s0 + sloc;
          bf16x8_t Bfrag = ldbf8(locu + sloc * 32 + kq * 8);
          float eacc = 0.f;
#pragma unroll
          for (int at = 0; at < 8; ++at) {
            f32x4_t C = {0,0,0,0};
            C = MFMA16(wLd[at], Bfrag, C);
            const ushort_t* pp = pmu + sloc * 128 + at * 16 + kq * 4;
#pragma unroll
            for (int r = 0; r < 4; ++r) {
              int a = at * 16 + kq * 4 + r;
              float val = C[r] + qsm[a] + bf2f(pp[r]);
              eacc = fmaf(vsm[a], ftanh(val), eacc);
            }
          }
          eacc += __shfl_xor(eacc, 16);
          eacc += __shfl_xor(eacc, 32);
          if (sglob >= mlenb) eacc = -1.0e9f;
          if (kq == 0) { esm[sglob] = eacc; eexG[b * 256 + sglob] = eacc; }
        }
        __syncthreads();
        // exchange e halves
        if (tid == 0) {
          __builtin_amdgcn_fence(__ATOMIC_RELEASE, "agent");
          __hip_atomic_store(eflag + (b * 2 + sh) * 16, t + 1, __ATOMIC_RELAXED, __HIP_MEMORY_SCOPE_AGENT);
          while (__hip_atomic_load(eflag + (b * 2 + 1 - sh) * 16, __ATOMIC_RELAXED, __HIP_MEMORY_SCOPE_AGENT) < t + 1)
            __builtin_amdgcn_s_sleep(1);
          __builtin_amdgcn_fence(__ATOMIC_ACQUIRE, "agent");
        }
        __syncthreads();
        if (tid < 128) esm[(1 - sh) * 128 + tid] = eexG[b * 256 + (1 - sh) * 128 + tid];
        __syncthreads();
        // softmax over full 256 (redundant in both halves)
        float ev = 0.f;
        if (tid < 256) {
          ev = esm[tid];
          float mv = ev;
          for (int o = 32; o; o >>= 1) mv = fmaxf(mv, __shfl_xor(mv, o));
          if (lane == 0) red[wid] = mv;
        }
        __syncthreads();
        float gmax = fmaxf(fmaxf(red[0], red[1]), fmaxf(red[2], red[3]));
        float pv = 0.f;
        if (tid < 256) {
          pv = __expf(ev - gmax);
          float sv = pv;
          for (int o = 32; o; o >>= 1) sv += __shfl_xor(sv, o);
          if (lane == 0) red[8 + wid] = sv;
        }
        __syncthreads();
        float gsum = red[8] + red[9] + red[10] + red[11];
        if (tid < 256) {
          float awv = pv / gsum;
          smaw[tid] = awv;
          smawc[tid] += awv;
          if ((tid >> 7) == sh) out_al[((size_t)b * 400 + t) * 256 + tid] = awv;
        }
        __syncthreads();
        if (tid == 0) {
          __builtin_amdgcn_fence(__ATOMIC_RELEASE, "agent");
          __hip_atomic_store(awfl + (b * 2 + sh) * 16, t + 1, __ATOMIC_RELAXED, __HIP_MEMORY_SCOPE_AGENT);
        }
      }
      gbar(bar, ++ep);
    }
  } else if (bid < 232) {
    // ======== PROJ path: mel/gate via Wdh.dh + M.aw ========
    const int wv = (bid - 224) * 8 + wid;   // 0..63
    int rows[2] = {wv * 2, wv * 2 + 1};
    float wdh[2][16], mreg[2][16][4], biasr[2];
#pragma unroll
    for (int rr = 0; rr < 2; ++rr) {
      int row = rows[rr];
      biasr[rr] = 0.f;
#pragma unroll
      for (int j = 0; j < 16; ++j) wdh[rr][j] = 0.f;
#pragma unroll
      for (int b2 = 0; b2 < 16; ++b2)
#pragma unroll
        for (int j = 0; j < 4; ++j) mreg[rr][b2][j] = 0.f;
      if (row <= 80) {
        const float* wsrc = (row < 80) ? p.Wproj + (size_t)row * 1536 : p.Wgate;
#pragma unroll
        for (int j = 0; j < 16; ++j) wdh[rr][j] = wsrc[lane + 64 * j];
        biasr[rr] = (row < 80) ? p.bproj[row] : p.bgate[0];
#pragma unroll
        for (int b2 = 0; b2 < 16; ++b2)
#pragma unroll
          for (int j = 0; j < 4; ++j)
            mreg[rr][b2][j] = Mx[((size_t)b2 * 81 + row) * 256 + lane + 64 * j];
      }
    }
    float* awp = sm;  // 4096
    __syncthreads();
    for (int t = 0; t <= TSTEPS; ++t) {
      gbar(bar, ++ep);  // PhX idle
      if (t >= 1) {
        for (int i = tid; i < 4096; i += 512) {
          int b2 = i >> 8, s = i & 255;
          awp[i] = out_al[((size_t)b2 * 400 + (t - 1)) * 256 + s];
        }
        __syncthreads();
        if (wv <= 40) {
          const size_t pp = (size_t)((t - 1) & 1) * 16384;
          for (int b2 = 0; b2 < 16; ++b2) {
            float h[16];
#pragma unroll
            for (int j = 0; j < 16; ++j) h[j] = dhfF[pp + b2 * 1024 + lane + 64 * j];
#pragma unroll
            for (int rr = 0; rr < 2; ++rr) {
              if (rows[rr] > 80) continue;
              float d = 0.f;
#pragma unroll
              for (int j = 0; j < 16; ++j) d = fmaf(wdh[rr][j], h[j], d);
#pragma unroll
              for (int j = 0; j < 4; ++j) d = fmaf(mreg[rr][b2][j], awp[b2 * 256 + lane + 64 * j], d);
              for (int o = 32; o; o >>= 1) d += __shfl_xor(d, o);
              if (lane == 0) {
                d += biasr[rr];
                if (rows[rr] < 80) out_mel[((size_t)b2 * 80 + rows[rr]) * 400 + (t - 1)] = d;
                else out_gate[(size_t)b2 * 400 + (t - 1)] = d;
              }
            }
          }
        }
        __syncthreads();
      }
      gbar(bar, ++ep);
    }
  } else {
    // ======== idle blocks ========
    for (int t = 0; t <= TSTEPS; ++t) {
      gbar(bar, ++ep);
      gbar(bar, ++ep);
    }
  }
}

extern "C" void kernel_launch(void* const* d_in, const int* in_sizes, int n_in,
                              void* d_out, int out_size, void* d_ws, size_t ws_size,
                              hipStream_t stream) {
  (void)in_sizes; (void)n_in; (void)out_size; (void)ws_size;
  Ptrs p;
  p.memory = (const float*)d_in[0];
  p.dec_in = (const float*)d_in[1];
  p.Wpre1  = (const float*)d_in[2];
  p.Wpre2  = (const float*)d_in[3];
  p.Wih_a  = (const float*)d_in[4];
  p.Whh_a  = (const float*)d_in[5];
  p.bih_a  = (const float*)d_in[6];
  p.bhh_a  = (const float*)d_in[7];
  p.Wq     = (const float*)d_in[8];
  p.Wm     = (const float*)d_in[9];
  p.v      = (const float*)d_in[10];
  p.Wc     = (const float*)d_in[11];
  p.Wld    = (const float*)d_in[12];
  p.Wih_d  = (const float*)d_in[13];
  p.Whh_d  = (const float*)d_in[14];
  p.bih_d  = (const float*)d_in[15];
  p.bhh_d  = (const float*)d_in[16];
  p.Wproj  = (const float*)d_in[17];
  p.bproj  = (const float*)d_in[18];
  p.Wgate  = (const float*)d_in[19];
  p.bgate  = (const float*)d_in[20];
  p.mlen   = (const int*)d_in[21];
  p.ws  = (float*)d_ws;
  p.out = (float*)d_out;

  hipLaunchKernelGGL(k_zero,      dim3((ZERO_COUNT + 255) / 256), dim3(256), 0, stream, p);
  hipLaunchKernelGGL(k_transpose, dim3(336), dim3(256), 0, stream, p);
  hipLaunchKernelGGL(k_prenet,    dim3(400), dim3(256), 0, stream, p);
  hipLaunchKernelGGL(k_procmem,   dim3(256), dim3(256), 0, stream, p);
  hipLaunchKernelGGL(k_premix,    dim3(16),  dim3(512), 0, stream, p);

  void* kargs[] = { (void*)&p };
  hipError_t err = hipLaunchCooperativeKernel(reinterpret_cast<const void*>(&k_scan),
                                              dim3(256), dim3(512), kargs, 0, stream);
  if (err != hipSuccess) {
    (void)hipGetLastError();
    hipLaunchKernelGGL(k_scan, dim3(256), dim3(512), 0, stream, p);
  }
}

// Round 6
// 16889.984 us; speedup vs baseline: 7.9703x; 1.0033x over previous
//
#include <hip/hip_runtime.h>

typedef unsigned short ushort_t;
typedef unsigned int uint_t;
typedef float f32x4_t __attribute__((ext_vector_type(4)));
typedef short bf16x8_t __attribute__((ext_vector_type(8)));

// ---- problem constants ----
#define NBATCH 16
#define SMEM   256
#define TSTEPS 400

// ---- workspace layout (float offsets) ----
#define F_XSB   0u         // 400*16*256 bf16 = 819200 floats
#define F_PM    819200u    // 16*256*128 f32
#define F_MMIX  1343488u   // 16*81*256 f32 (M_b = Wctx . mem^T)
#define F_W1T   1675264u
#define F_W2T   1695744u
// ---- zeroed region ----
#define F_AHB   1761280u   // 2*16*1024 bf16 = 16384 floats
#define F_DHB   1777664u   // 16384
#define F_CTXB  1794048u   // 2*16*512 bf16 = 8192 floats
#define F_DHF   1802240u   // 2*16*1024 f32 = 32768
#define F_AWG   1835008u   // 2*16*256 f32 = 8192
#define F_FLG   1843200u   // 344 slots * 16 ints = 5504
#define ZERO_BASE  F_AHB
#define ZERO_COUNT 87424u

// flag slot bases
#define AHF  0
#define CTXF 64
#define DHFL 192
#define AWF  320
#define PRF  336

struct Ptrs {
  const float *memory, *dec_in, *Wpre1, *Wpre2, *Wih_a, *Whh_a, *bih_a, *bhh_a,
              *Wq, *Wm, *v, *Wc, *Wld, *Wih_d, *Whh_d, *bih_d, *bhh_d,
              *Wproj, *bproj, *Wgate, *bgate;
  const int *mlen;
  float *ws;
  float *out;
};

__device__ __forceinline__ float ftanh(float x) {
  float e = __expf(2.f * x);
  return 1.f - 2.f / (e + 1.f);
}
__device__ __forceinline__ float fsig(float x) { return 1.f / (1.f + __expf(-x)); }

__device__ __forceinline__ unsigned f2bfbits(float x) {
  unsigned u = __builtin_bit_cast(unsigned, x);
  return (u + 0x7FFFu + ((u >> 16) & 1u)) >> 16;
}
__device__ __forceinline__ float bf2f(ushort_t u) {
  unsigned v = ((unsigned)u) << 16;
  return __builtin_bit_cast(float, v);
}
__device__ __forceinline__ bf16x8_t packbf8(const float* f) {
  bf16x8_t r;
#pragma unroll
  for (int j = 0; j < 8; ++j) r[j] = (short)f2bfbits(f[j]);
  return r;
}
__device__ __forceinline__ bf16x8_t pack_from_f4(const float* src) {
  const float4* s4 = (const float4*)src;
  float4 lo = s4[0], hi = s4[1];
  float tmp[8] = {lo.x, lo.y, lo.z, lo.w, hi.x, hi.y, hi.z, hi.w};
  return packbf8(tmp);
}
__device__ __forceinline__ bf16x8_t ldbf8(const ushort_t* p) {
  return *(const bf16x8_t*)p;
}
struct ull2 { unsigned long long x, y; };
__device__ __forceinline__ bf16x8_t ldbf8_a(const ushort_t* p) {
  ull2 v;
  v.x = __hip_atomic_load((const unsigned long long*)p, __ATOMIC_RELAXED, __HIP_MEMORY_SCOPE_AGENT);
  v.y = __hip_atomic_load(((const unsigned long long*)p) + 1, __ATOMIC_RELAXED, __HIP_MEMORY_SCOPE_AGENT);
  return __builtin_bit_cast(bf16x8_t, v);
}
__device__ __forceinline__ void stull_a(unsigned long long* p, unsigned long long v) {
  __hip_atomic_store(p, v, __ATOMIC_RELAXED, __HIP_MEMORY_SCOPE_AGENT);
}
__device__ __forceinline__ void stf_a(float* p, float v) {
  __hip_atomic_store(p, v, __ATOMIC_RELAXED, __HIP_MEMORY_SCOPE_AGENT);
}
__device__ __forceinline__ float ldf_a(const float* p) {
  return __hip_atomic_load(p, __ATOMIC_RELAXED, __HIP_MEMORY_SCOPE_AGENT);
}
__device__ __forceinline__ void pollge(int* flg, int slot, int thr) {
  while (__hip_atomic_load(flg + slot * 16, __ATOMIC_RELAXED, __HIP_MEMORY_SCOPE_AGENT) < thr)
    __builtin_amdgcn_s_sleep(1);
}
__device__ __forceinline__ void sig(int* flg, int slot, int val) {
  __hip_atomic_store(flg + slot * 16, val, __ATOMIC_RELAXED, __HIP_MEMORY_SCOPE_AGENT);
}
#define MFMA16(a,b,c) __builtin_amdgcn_mfma_f32_16x16x32_bf16((a),(b),(c),0,0,0)

// ---------------- zero state ----------------
__global__ __launch_bounds__(256) void k_zero(Ptrs p) {
  unsigned i = blockIdx.x * 256 + threadIdx.x;
  if (i < ZERO_COUNT) p.ws[ZERO_BASE + i] = 0.f;
}

// ---------------- weight transposes for prenet ----------------
__global__ __launch_bounds__(256) void k_transpose(Ptrs p) {
  int i = blockIdx.x * 256 + threadIdx.x;
  if (i < 20480) {
    int m = i >> 8, c = i & 255;
    p.ws[F_W1T + i] = p.Wpre1[c * 80 + m];
  } else if (i < 20480 + 65536) {
    int j = i - 20480;
    int pp = j >> 8, q = j & 255;
    p.ws[F_W2T + j] = p.Wpre2[q * 256 + pp];
  }
}

// ---------------- prenet -> xsb (bf16) ----------------
__global__ __launch_bounds__(256) void k_prenet(Ptrs p) {
  __shared__ float dil[NBATCH * 80];
  __shared__ float h1[NBATCH * 256];
  const int t = blockIdx.x, tid = threadIdx.x;
  const float* W1T = p.ws + F_W1T;
  const float* W2T = p.ws + F_W2T;

  for (int i = tid; i < NBATCH * 80; i += 256) {
    int b = i / 80, m = i - b * 80;
    dil[i] = (t == 0) ? 0.f : p.dec_in[((size_t)b * 80 + m) * 400 + (t - 1)];
  }
  __syncthreads();

  float acc[NBATCH];
#pragma unroll
  for (int b = 0; b < NBATCH; ++b) acc[b] = 0.f;
  for (int m = 0; m < 80; ++m) {
    float w = W1T[m * 256 + tid];
#pragma unroll
    for (int b = 0; b < NBATCH; ++b) acc[b] = fmaf(dil[b * 80 + m], w, acc[b]);
  }
#pragma unroll
  for (int b = 0; b < NBATCH; ++b) h1[b * 256 + tid] = fmaxf(acc[b], 0.f);
  __syncthreads();

#pragma unroll
  for (int b = 0; b < NBATCH; ++b) acc[b] = 0.f;
  for (int q = 0; q < 256; ++q) {
    float w = W2T[q * 256 + tid];
#pragma unroll
    for (int b = 0; b < NBATCH; ++b) acc[b] = fmaf(h1[b * 256 + q], w, acc[b]);
  }
  ushort_t* xsbU = (ushort_t*)(p.ws + F_XSB);
#pragma unroll
  for (int b = 0; b < NBATCH; ++b)
    xsbU[((size_t)(t * NBATCH + b)) * 256 + tid] = (ushort_t)f2bfbits(fmaxf(acc[b], 0.f));
}

// ---------------- proc_mem fp32 ----------------
__global__ __launch_bounds__(256) void k_procmem(Ptrs p) {
  __shared__ alignas(16) float msl[16 * 512];
  const int b = blockIdx.x >> 4, s0 = (blockIdx.x & 15) << 4;
  const int tid = threadIdx.x;
  const float4* src = (const float4*)(p.memory + ((size_t)(b * SMEM + s0)) * 512);
  float4* dst = (float4*)msl;
  for (int i = tid; i < 16 * 512 / 4; i += 256) dst[i] = src[i];
  __syncthreads();

  const int a = tid & 127, sg = tid >> 7;
  const float4* wm = (const float4*)(p.Wm + (size_t)a * 512);
  float* pm = p.ws + F_PM;
  float acc[8];
#pragma unroll
  for (int j = 0; j < 8; ++j) acc[j] = 0.f;
  for (int k = 0; k < 128; ++k) {
    float4 w = wm[k];
#pragma unroll
    for (int j = 0; j < 8; ++j) {
      float4 m = ((const float4*)(msl + (size_t)(sg * 8 + j) * 512))[k];
      acc[j] += w.x * m.x + w.y * m.y + w.z * m.z + w.w * m.w;
    }
  }
#pragma unroll
  for (int j = 0; j < 8; ++j)
    pm[((size_t)(b * SMEM + s0 + sg * 8 + j)) * 128 + a] = acc[j];
}

// ---------------- premix: M[b][row][s] = Wctx[row][:] . memory[b][s][:] ----------------
__global__ __launch_bounds__(512) void k_premix(Ptrs p) {
  const int b = blockIdx.x, tid = threadIdx.x;
  float* M = p.ws + F_MMIX;
  for (int i = tid; i < 81 * 256; i += 512) {
    int row = i >> 8, s = i & 255;
    const float* wrow = (row < 80) ? p.Wproj + (size_t)row * 1536 + 1024 : p.Wgate + 1024;
    const float4* w4 = (const float4*)wrow;
    const float4* m4 = (const float4*)(p.memory + ((size_t)(b * 256 + s)) * 512);
    float acc = 0.f;
#pragma unroll 4
    for (int k = 0; k < 128; ++k) {
      float4 w = w4[k], m = m4[k];
      acc += w.x * m.x + w.y * m.y + w.z * m.z + w.w * m.w;
    }
    M[((size_t)b * 81 + row) * 256 + s] = acc;
  }
}

// ---------------- persistent dataflow scan: 256 blocks x 512 threads ----------------
__global__ __launch_bounds__(512, 1) void k_scan(Ptrs p) {
  __shared__ alignas(16) float sm[12288];   // 48 KB
  const int bid = blockIdx.x, tid = threadIdx.x;
  const int wid = tid >> 6, lane = tid & 63;
  const int m16 = lane & 15, kq = lane >> 4;

  float* ws = p.ws;
  ushort_t* xsbU  = (ushort_t*)(ws + F_XSB);
  float*    pmF   = ws + F_PM;
  float*    Mx    = ws + F_MMIX;
  ushort_t* ahbU  = (ushort_t*)(ws + F_AHB);
  unsigned long long* ahb8 = (unsigned long long*)(ws + F_AHB);
  ushort_t* dhbU  = (ushort_t*)(ws + F_DHB);
  unsigned long long* dhb8 = (unsigned long long*)(ws + F_DHB);
  ushort_t* ctxbU = (ushort_t*)(ws + F_CTXB);
  unsigned long long* ctxb8 = (unsigned long long*)(ws + F_CTXB);
  float*    dhfF  = ws + F_DHF;
  float*    awGF  = ws + F_AWG;
  int*      flg   = (int*)(ws + F_FLG);
  float* out_mel  = p.out;
  float* out_gate = p.out + 512000;
  float* out_al   = p.out + 518400;

  if (bid < 64) {
    // ======== A-path: A-LSTM(t); 8 waves = 4 strips x 2 K-halves ========
    const int ls = wid >> 1, half = wid & 1;
    const int strip = (bid << 2) | ls;
    const int gA = m16 & 3, jA = m16 >> 2;
    const int wrowA = gA * 1024 + strip * 4 + jA;
    bf16x8_t wA[28];
#pragma unroll
    for (int c = 0; c < 28; ++c) {
      int k0 = (half * 28 + c) * 32 + kq * 8;
      const float* src = (k0 < 768) ? p.Wih_a + (size_t)wrowA * 768 + k0
                                    : p.Whh_a + (size_t)wrowA * 1024 + (k0 - 768);
      wA[c] = pack_from_f4(src);
    }
    const int nnA = strip * 4 + kq;
    float biasA[4];
#pragma unroll
    for (int r = 0; r < 4; ++r) biasA[r] = p.bih_a[r * 1024 + nnA] + p.bhh_a[r * 1024 + nnA];
    float acState = 0.f;
    __syncthreads();

    for (int t = 0; t < TSTEPS; ++t) {
      const int pc = t & 1, pp = (t + 1) & 1;
      // waits: ah(t-1), ctx(t-1), proj lag guard
      if (tid < 64) pollge(flg, AHF + tid, t);
      else if (tid < 192) pollge(flg, CTXF + tid - 64, t);
      else if (tid < 200) pollge(flg, PRF + tid - 192, t - 1);
      __syncthreads();

      f32x4_t a0 = {0,0,0,0}, a1 = {0,0,0,0};
      const ushort_t* xsrc = xsbU + ((size_t)t * 16 + m16) * 256;
      const ushort_t* csrc = ctxbU + (size_t)pp * 8192 + m16 * 512;
      const ushort_t* hsrc = ahbU + (size_t)pp * 16384 + m16 * 1024;
      if (half == 0) {
#pragma unroll
        for (int c = 0; c < 28; ++c) {
          bf16x8_t bf;
          if (c < 8)       bf = ldbf8(xsrc + c * 32 + kq * 8);
          else if (c < 24) bf = ldbf8_a(csrc + (c - 8) * 32 + kq * 8);
          else             bf = ldbf8_a(hsrc + (c - 24) * 32 + kq * 8);
          if (c & 1) a1 = MFMA16(wA[c], bf, a1); else a0 = MFMA16(wA[c], bf, a0);
        }
      } else {
#pragma unroll
        for (int c = 0; c < 28; ++c) {
          bf16x8_t bf = ldbf8_a(hsrc + (4 + c) * 32 + kq * 8);
          if (c & 1) a1 = MFMA16(wA[c], bf, a1); else a0 = MFMA16(wA[c], bf, a0);
        }
#pragma unroll
        for (int r = 0; r < 4; ++r) sm[((ls * 64 + lane) << 2) + r] = a0[r] + a1[r];
      }
      __syncthreads();
      if (half == 0) {
        float z[4];
#pragma unroll
        for (int r = 0; r < 4; ++r)
          z[r] = a0[r] + a1[r] + sm[((ls * 64 + lane) << 2) + r] + biasA[r];
        float cn = fsig(z[1]) * acState + fsig(z[0]) * ftanh(z[2]);
        acState = cn;
        float h = fsig(z[3]) * ftanh(cn);
        unsigned hb = f2bfbits(h);
        unsigned b0 = __shfl(hb, m16);
        unsigned b1 = __shfl(hb, m16 + 16);
        unsigned b2 = __shfl(hb, m16 + 32);
        unsigned b3 = __shfl(hb, m16 + 48);
        if (kq == 0) {
          unsigned long long u = (unsigned long long)(b0 | (b1 << 16))
                               | ((unsigned long long)(b2 | (b3 << 16)) << 32);
          stull_a(ahb8 + ((size_t)(pc * 16 + m16)) * 256 + strip, u);
        }
      }
      __syncthreads();   // drains all waves' stores (vmcnt) before flag
      if (tid == 0) sig(flg, AHF + bid, t + 1);
    }
  } else if (bid < 192) {
    // ======== D-path: D-LSTM(t-1) then ctx(t) slice ========
    const int ls = wid >> 2, qt = wid & 3;
    const int strip = ((bid - 64) << 1) | ls;
    const int gD = m16 & 3, jD = m16 >> 2;
    const int wrowD = gD * 1024 + strip * 4 + jD;
    bf16x8_t wD[20];
#pragma unroll
    for (int c = 0; c < 20; ++c) {
      int k0 = (qt * 20 + c) * 32 + kq * 8;
      const float* src = (k0 < 1536) ? p.Wih_d + (size_t)wrowD * 1536 + k0
                                     : p.Whh_d + (size_t)wrowD * 1024 + (k0 - 1536);
      wD[c] = pack_from_f4(src);
    }
    const int nnD = strip * 4 + kq;
    float biasD[4];
#pragma unroll
    for (int r = 0; r < 4; ++r) biasD[r] = p.bih_d[r * 1024 + nnD] + p.bhh_d[r * 1024 + nnD];
    float dcState = 0.f;

    const int cb = (bid - 64) >> 3, sl = (bid - 64) & 7;
    float* comb = sm;               // 1536
    float* awsm = sm + 1536;        // 256
    float* part = sm + 1792;        // 512
    ushort_t* memu = (ushort_t*)(sm + 2304);   // 16384 ushorts
    for (int i = tid; i < 16384; i += 512) {
      int s = i >> 6, c = i & 63;
      memu[i] = (ushort_t)f2bfbits(p.memory[((size_t)cb * 256 + s) * 512 + sl * 64 + c]);
    }
    __syncthreads();

    for (int t = 0; t <= TSTEPS; ++t) {
      const int pc = t & 1, pw = (t + 1) & 1;
      if (t >= 1) {
        // waits: ah(t-1), ctx(t-1), dh(t-2)
        if (tid < 64) pollge(flg, AHF + tid, t);
        else if (tid < 192) pollge(flg, CTXF + tid - 64, t);
        else if (tid < 320) pollge(flg, DHFL + tid - 192, t - 1);
        __syncthreads();

        f32x4_t a0 = {0,0,0,0}, a1 = {0,0,0,0};
        const ushort_t* hsrc = ahbU + (size_t)pw * 16384 + m16 * 1024;
        const ushort_t* csrc = ctxbU + (size_t)pw * 8192 + m16 * 512;
        const ushort_t* dsrc = dhbU + (size_t)pc * 16384 + m16 * 1024;
#define DMFMA(SRC, OFF) { bf16x8_t bf = ldbf8_a((SRC) + (OFF) * 32 + kq * 8); \
          if (c & 1) a1 = MFMA16(wD[c], bf, a1); else a0 = MFMA16(wD[c], bf, a0); }
        if (qt == 0) {
#pragma unroll
          for (int c = 0; c < 20; ++c) DMFMA(hsrc, c)
        } else if (qt == 1) {
#pragma unroll
          for (int c = 0; c < 20; ++c) { if (c < 12) DMFMA(hsrc, 20 + c) else DMFMA(csrc, c - 12) }
        } else if (qt == 2) {
#pragma unroll
          for (int c = 0; c < 20; ++c) { if (c < 8) DMFMA(csrc, 8 + c) else DMFMA(dsrc, c - 8) }
        } else {
#pragma unroll
          for (int c = 0; c < 20; ++c) DMFMA(dsrc, 12 + c)
        }
#undef DMFMA
        if (qt != 0) {
#pragma unroll
          for (int r = 0; r < 4; ++r)
            comb[(((ls * 3 + qt - 1) * 64 + lane) << 2) + r] = a0[r] + a1[r];
        }
        __syncthreads();
        if (qt == 0) {
          float z[4];
#pragma unroll
          for (int r = 0; r < 4; ++r) {
            z[r] = a0[r] + a1[r] + biasD[r];
#pragma unroll
            for (int j = 0; j < 3; ++j) z[r] += comb[(((ls * 3 + j) * 64 + lane) << 2) + r];
          }
          float cn = fsig(z[1]) * dcState + fsig(z[0]) * ftanh(z[2]);
          dcState = cn;
          float h = fsig(z[3]) * ftanh(cn);
          stf_a(dhfF + (size_t)pw * 16384 + m16 * 1024 + nnD, h);
          unsigned hb = f2bfbits(h);
          unsigned b0 = __shfl(hb, m16);
          unsigned b1 = __shfl(hb, m16 + 16);
          unsigned b2 = __shfl(hb, m16 + 32);
          unsigned b3 = __shfl(hb, m16 + 48);
          if (kq == 0) {
            unsigned long long u = (unsigned long long)(b0 | (b1 << 16))
                                 | ((unsigned long long)(b2 | (b3 << 16)) << 32);
            stull_a(dhb8 + ((size_t)(pw * 16 + m16)) * 256 + strip, u);
          }
        }
        __syncthreads();
        if (tid == 0) sig(flg, DHFL + (bid - 64), t);
      }
      if (t < TSTEPS) {
        // ctx(t): wait aw(t)
        if (tid == 0) pollge(flg, AWF + cb, t + 1);
        __syncthreads();
        if (tid < 256) awsm[tid] = ldf_a(awGF + (size_t)pc * 4096 + cb * 256 + tid);
        __syncthreads();
        const int c = tid & 63, sg = tid >> 6;
        float acc = 0.f;
#pragma unroll 8
        for (int si = 0; si < 32; ++si) {
          int s = sg * 32 + si;
          acc = fmaf(awsm[s], bf2f(memu[s * 64 + c]), acc);
        }
        part[sg * 64 + c] = acc;
        __syncthreads();
        if (tid < 64) {
          float v = 0.f;
#pragma unroll
          for (int j = 0; j < 8; ++j) v += part[j * 64 + tid];
          unsigned vb = f2bfbits(v);
          int base = tid & ~3;
          unsigned c0 = __shfl(vb, base);
          unsigned c1 = __shfl(vb, base + 1);
          unsigned c2 = __shfl(vb, base + 2);
          unsigned c3 = __shfl(vb, base + 3);
          if ((tid & 3) == 0) {
            unsigned long long u = (unsigned long long)(c0 | (c1 << 16))
                                 | ((unsigned long long)(c2 | (c3 << 16)) << 32);
            stull_a(ctxb8 + ((size_t)(pc * 16 + cb)) * 128 + ((sl * 64 + tid) >> 2), u);
          }
        }
        __syncthreads();
        if (tid == 0) sig(flg, CTXF + (bid - 64), t + 1);
      }
    }
  } else if (bid < 208) {
    // ======== ATT path: one block per batch ========
    const int b = bid - 192;
    const int mlenb = p.mlen[b];
    ushort_t* locu = (ushort_t*)sm;        // 256*40 ushorts = 5120 floats
    float* qsm   = sm + 5120;
    float* vsm   = sm + 5248;
    float* esm   = sm + 5376;
    float* red   = sm + 5632;
    float* smaw  = sm + 5648;
    float* smawc = sm + 5904;

    bf16x8_t wq[32];
#pragma unroll
    for (int c = 0; c < 32; ++c)
      wq[c] = pack_from_f4(p.Wq + (size_t)(wid * 16 + m16) * 1024 + c * 32 + kq * 8);
    bf16x8_t wLd[8];
#pragma unroll
    for (int at = 0; at < 8; ++at)
      wLd[at] = pack_from_f4(p.Wld + ((size_t)(at * 16 + m16)) * 32 + kq * 8);
    bf16x8_t wC[2][2];
#pragma unroll
    for (int ft = 0; ft < 2; ++ft)
#pragma unroll
      for (int ck = 0; ck < 2; ++ck) {
        float tmp[8];
#pragma unroll
        for (int jj = 0; jj < 8; ++jj) {
          int k2 = ck * 32 + kq * 8 + jj;
          float vv = 0.f;
          if (k2 < 62) { int ch = (k2 < 31) ? 0 : 1; int k = k2 - 31 * ch;
            vv = p.Wc[((size_t)(ft * 16 + m16) * 2 + ch) * 31 + k]; }
          tmp[jj] = vv;
        }
        wC[ft][ck] = packbf8(tmp);
      }
    // pm -> registers: per wave 2 s-tiles (wid*2+u), lane row m16, a=at*16+kq*4+r
    uint_t pmreg[2][8][2];
#pragma unroll
    for (int u = 0; u < 2; ++u) {
      int sloc = (wid * 2 + u) * 16 + m16;
#pragma unroll
      for (int at = 0; at < 8; ++at)
#pragma unroll
        for (int rp = 0; rp < 2; ++rp) {
          const float* src = pmF + ((size_t)(b * 256 + sloc)) * 128 + at * 16 + kq * 4 + rp * 2;
          pmreg[u][at][rp] = f2bfbits(src[0]) | (f2bfbits(src[1]) << 16);
        }
    }
    if (tid < 128) vsm[tid] = p.v[tid];
    if (tid < 256) { smaw[tid] = 0.f; smawc[tid] = 0.f; }
    __syncthreads();

    for (int t = 0; t < TSTEPS; ++t) {
      const int pc = t & 1;
      // conv(t) from LDS aw/awc (ready since prev iter): 4 tasks/wave
#pragma unroll
      for (int u = 0; u < 4; ++u) {
        int task = wid * 4 + u;
        int stile = task >> 1, ft = task & 1;
        int scol = stile * 16 + m16;
        f32x4_t acc = {0,0,0,0};
#pragma unroll
        for (int ck = 0; ck < 2; ++ck) {
          float tmp[8];
#pragma unroll
          for (int jj = 0; jj < 8; ++jj) {
            int k2 = ck * 32 + kq * 8 + jj;
            float vv = 0.f;
            if (k2 < 62) {
              int ch = (k2 < 31) ? 0 : 1; int k = k2 - 31 * ch;
              int sp = scol + k - 15;
              if (sp >= 0 && sp < 256) vv = (ch ? smawc : smaw)[sp];
            }
            tmp[jj] = vv;
          }
          acc = MFMA16(wC[ft][ck], packbf8(tmp), acc);
        }
#pragma unroll
        for (int r = 0; r < 4; ++r)
          locu[scol * 40 + ft * 16 + kq * 4 + r] = (ushort_t)f2bfbits(acc[r]);
      }
      // wait ah(t)
      if (tid < 64) pollge(flg, AHF + tid, t + 1);
      __syncthreads();
      // q = Wq . ah(t)
      {
        f32x4_t acc = {0,0,0,0};
        const ushort_t* hsrc = ahbU + (size_t)pc * 16384 + m16 * 1024;
#pragma unroll
        for (int c = 0; c < 32; ++c) {
          bf16x8_t bf = ldbf8_a(hsrc + c * 32 + kq * 8);
          acc = MFMA16(wq[c], bf, acc);
        }
        if (m16 == b) {
#pragma unroll
          for (int r = 0; r < 4; ++r) qsm[wid * 16 + kq * 4 + r] = acc[r];
        }
      }
      __syncthreads();
      // fused pa+e: 2 s-tiles per wave, pm from registers
#pragma unroll
      for (int u = 0; u < 2; ++u) {
        int sloc = (wid * 2 + u) * 16 + m16;
        bf16x8_t Bfrag = ldbf8(locu + sloc * 40 + kq * 8);
        float eacc = 0.f;
#pragma unroll
        for (int at = 0; at < 8; ++at) {
          f32x4_t C = {0,0,0,0};
          C = MFMA16(wLd[at], Bfrag, C);
#pragma unroll
          for (int r = 0; r < 4; ++r) {
            int a = at * 16 + kq * 4 + r;
            uint_t pw_ = pmreg[u][at][r >> 1];
            float pmv = bf2f((ushort_t)((r & 1) ? (pw_ >> 16) : (pw_ & 0xFFFF)));
            eacc = fmaf(vsm[a], ftanh(C[r] + qsm[a] + pmv), eacc);
          }
        }
        eacc += __shfl_xor(eacc, 16);
        eacc += __shfl_xor(eacc, 32);
        if (sloc >= mlenb) eacc = -1.0e9f;
        if (kq == 0) esm[sloc] = eacc;
      }
      __syncthreads();
      // softmax over 256
      float ev = 0.f;
      if (tid < 256) {
        ev = esm[tid];
        float mv = ev;
        for (int o = 32; o; o >>= 1) mv = fmaxf(mv, __shfl_xor(mv, o));
        if (lane == 0) red[wid] = mv;
      }
      __syncthreads();
      float gmax = fmaxf(fmaxf(red[0], red[1]), fmaxf(red[2], red[3]));
      float pv = 0.f;
      if (tid < 256) {
        pv = __expf(ev - gmax);
        float sv = pv;
        for (int o = 32; o; o >>= 1) sv += __shfl_xor(sv, o);
        if (lane == 0) red[8 + wid] = sv;
      }
      __syncthreads();
      float gsum = red[8] + red[9] + red[10] + red[11];
      if (tid < 256) {
        float awv = pv / gsum;
        smaw[tid] = awv;
        smawc[tid] += awv;
        out_al[((size_t)b * 400 + t) * 256 + tid] = awv;
        stf_a(awGF + (size_t)pc * 4096 + b * 256 + tid, awv);
      }
      __syncthreads();
      if (tid == 0) sig(flg, AWF + b, t + 1);
    }
  } else if (bid < 216) {
    // ======== PROJ path: mel/gate = Wdh.dh(t-1) + M.aw(t-1) + bias ========
    const int wv = (bid - 208) * 8 + wid;   // 0..63
    int rows[2] = {wv * 2, wv * 2 + 1};
    float wdh[2][16], mreg[2][16][4], biasr[2];
#pragma unroll
    for (int rr = 0; rr < 2; ++rr) {
      int row = rows[rr];
      biasr[rr] = 0.f;
#pragma unroll
      for (int j = 0; j < 16; ++j) wdh[rr][j] = 0.f;
#pragma unroll
      for (int b2 = 0; b2 < 16; ++b2)
#pragma unroll
        for (int j = 0; j < 4; ++j) mreg[rr][b2][j] = 0.f;
      if (row <= 80) {
        const float* wsrc = (row < 80) ? p.Wproj + (size_t)row * 1536 : p.Wgate;
#pragma unroll
        for (int j = 0; j < 16; ++j) wdh[rr][j] = wsrc[lane + 64 * j];
        biasr[rr] = (row < 80) ? p.bproj[row] : p.bgate[0];
#pragma unroll
        for (int b2 = 0; b2 < 16; ++b2)
#pragma unroll
          for (int j = 0; j < 4; ++j)
            mreg[rr][b2][j] = Mx[((size_t)b2 * 81 + row) * 256 + lane + 64 * j];
      }
    }
    float* awp = sm;  // 4096
    __syncthreads();
    for (int t = 1; t <= TSTEPS; ++t) {
      const int pw = (t + 1) & 1;
      if (tid < 128) pollge(flg, DHFL + tid, t);
      else if (tid < 144) pollge(flg, AWF + tid - 128, t);
      __syncthreads();
      for (int i = tid; i < 4096; i += 512)
        awp[i] = ldf_a(awGF + (size_t)pw * 4096 + i);
      __syncthreads();
      if (wv <= 40) {
        const size_t pp = (size_t)pw * 16384;
        for (int b2 = 0; b2 < 16; ++b2) {
          float h[16];
#pragma unroll
          for (int j = 0; j < 16; ++j) h[j] = ldf_a(dhfF + pp + b2 * 1024 + lane + 64 * j);
#pragma unroll
          for (int rr = 0; rr < 2; ++rr) {
            if (rows[rr] > 80) continue;
            float d = 0.f;
#pragma unroll
            for (int j = 0; j < 16; ++j) d = fmaf(wdh[rr][j], h[j], d);
#pragma unroll
            for (int j = 0; j < 4; ++j) d = fmaf(mreg[rr][b2][j], awp[b2 * 256 + lane + 64 * j], d);
            for (int o = 32; o; o >>= 1) d += __shfl_xor(d, o);
            if (lane == 0) {
              d += biasr[rr];
              if (rows[rr] < 80) out_mel[((size_t)b2 * 80 + rows[rr]) * 400 + (t - 1)] = d;
              else out_gate[(size_t)b2 * 400 + (t - 1)] = d;
            }
          }
        }
      }
      __syncthreads();
      if (tid == 0) sig(flg, PRF + (bid - 208), t);
    }
  }
  // bid >= 216: exit immediately
}

extern "C" void kernel_launch(void* const* d_in, const int* in_sizes, int n_in,
                              void* d_out, int out_size, void* d_ws, size_t ws_size,
                              hipStream_t stream) {
  (void)in_sizes; (void)n_in; (void)out_size; (void)ws_size;
  Ptrs p;
  p.memory = (const float*)d_in[0];
  p.dec_in = (const float*)d_in[1];
  p.Wpre1  = (const float*)d_in[2];
  p.Wpre2  = (const float*)d_in[3];
  p.Wih_a  = (const float*)d_in[4];
  p.Whh_a  = (const float*)d_in[5];
  p.bih_a  = (const float*)d_in[6];
  p.bhh_a  = (const float*)d_in[7];
  p.Wq     = (const float*)d_in[8];
  p.Wm     = (const float*)d_in[9];
  p.v      = (const float*)d_in[10];
  p.Wc     = (const float*)d_in[11];
  p.Wld    = (const float*)d_in[12];
  p.Wih_d  = (const float*)d_in[13];
  p.Whh_d  = (const float*)d_in[14];
  p.bih_d  = (const float*)d_in[15];
  p.bhh_d  = (const float*)d_in[16];
  p.Wproj  = (const float*)d_in[17];
  p.bproj  = (const float*)d_in[18];
  p.Wgate  = (const float*)d_in[19];
  p.bgate  = (const float*)d_in[20];
  p.mlen   = (const int*)d_in[21];
  p.ws  = (float*)d_ws;
  p.out = (float*)d_out;

  hipLaunchKernelGGL(k_zero,      dim3((ZERO_COUNT + 255) / 256), dim3(256), 0, stream, p);
  hipLaunchKernelGGL(k_transpose, dim3(336), dim3(256), 0, stream, p);
  hipLaunchKernelGGL(k_prenet,    dim3(400), dim3(256), 0, stream, p);
  hipLaunchKernelGGL(k_procmem,   dim3(256), dim3(256), 0, stream, p);
  hipLaunchKernelGGL(k_premix,    dim3(16),  dim3(512), 0, stream, p);
  hipLaunchKernelGGL(k_scan,      dim3(256), dim3(512), 0, stream, p);
}